// Round 1
// baseline (1698.560 us; speedup 1.0000x reference)
//
#include <hip/hip_runtime.h>
#include <math.h>

#define B_N   2048
#define NM    128
#define M_N   256
#define LNUM  10
#define EPS_Sf 1e-6f

// ---------------- workspace layout (float offsets) ----------------
static constexpr size_t o_AA  = 0;                       // float2[256*256] -> 131072 floats
static constexpr size_t o_D   = o_AA  + 131072;          // 256
static constexpr size_t o_yn  = o_D   + 256;             // 2048
static constexpr size_t o_AY  = o_yn  + 2048;            // float2[B*M] -> 1048576 floats
static constexpr size_t o_AYt = o_AY  + 1048576;         // [2][256][2048] = 1048576
static constexpr size_t o_w2t = o_AYt + 1048576;         // [ic][dm][db][oc] 18432
static constexpr size_t o_z1  = o_w2t + 18432;           // [32][256][2048] = 16777216
static constexpr size_t o_fp  = o_z1  + 16777216;        // [16][64][2048] = 2097152
static constexpr size_t o_f   = o_fp  + 2097152;         // [64][2048] = 131072
static constexpr size_t o_c   = o_f   + 131072;          // [2048][9]
static constexpr size_t o_dd  = o_c   + 18432;           // [2048][9]
static constexpr size_t o_T   = o_dd  + 18432;           // [2048][10]
static constexpr size_t o_Ua  = o_T   + 20480;           // 524288
static constexpr size_t o_gm  = o_Ua  + 524288;          // 1 (uint bits of max)
// total ~21.84M floats = ~87.4 MB

// ---------------- K0: AA = A^H A  (exactly Hermitian), D = diag ----------------
__global__ void k_aa(const float* __restrict__ Ar, const float* __restrict__ Ai,
                     float* __restrict__ ws) {
    __shared__ float cr[NM], ci[NM];
    int i = blockIdx.x, j = threadIdx.x;
    if (j < NM) { cr[j] = Ar[j * M_N + i]; ci[j] = Ai[j * M_N + i]; }
    __syncthreads();
    float sr = 0.f, si = 0.f;
    for (int n = 0; n < NM; ++n) {
        float ar = Ar[n * M_N + j], ai = Ai[n * M_N + j];
        sr += cr[n] * ar + ci[n] * ai;   // Re(conj(A[n,i])*A[n,j])
        si += cr[n] * ai - ci[n] * ar;   // Im
    }
    float2* AA = (float2*)(ws + o_AA);
    AA[(size_t)i * M_N + j] = make_float2(sr, si);
    if (j == i) ws[o_D + i] = sr;
}

// ---------------- K0b: transpose conv2_w -> [ic][dm][db][oc] ----------------
__global__ void k_w2t(const float* __restrict__ w2, float* __restrict__ ws) {
    int i = blockIdx.x * 256 + threadIdx.x;
    if (i < 64 * 32 * 9) {
        int oc = i / 288, r = i % 288;          // r = ic*9 + dm*3 + db
        int ic = r / 9, dm = (r % 9) / 3, db = r % 3;
        ws[o_w2t + ((size_t)((ic * 3 + dm) * 3 + db)) * 64 + oc] = w2[i];
    }
}

// ---------------- K1: AY = A^H Y, ||Y||^2, and transposed layout for conv ----------------
__global__ void k_ay(const float* __restrict__ Yr, const float* __restrict__ Yi,
                     const float* __restrict__ Ar, const float* __restrict__ Ai,
                     float* __restrict__ ws) {
    __shared__ float2 Ys[8][NM];
    int bb0 = blockIdx.x * 8;
    int tid = threadIdx.x;
    for (int i = tid; i < 8 * NM; i += 256) {
        int g = i >> 7, n = i & 127;
        Ys[g][n] = make_float2(Yr[(size_t)(bb0 + g) * NM + n], Yi[(size_t)(bb0 + g) * NM + n]);
    }
    __syncthreads();
    if (tid < 8) {
        float s = 0.f;
        for (int n = 0; n < NM; ++n) { float2 y = Ys[tid][n]; s += y.x * y.x + y.y * y.y; }
        ws[o_yn + bb0 + tid] = s;
    }
    int m = tid;
    float accr[8], acci[8];
#pragma unroll
    for (int g = 0; g < 8; ++g) { accr[g] = 0.f; acci[g] = 0.f; }
    for (int n = 0; n < NM; ++n) {
        float ar = Ar[n * M_N + m], ai = Ai[n * M_N + m];
#pragma unroll
        for (int g = 0; g < 8; ++g) {
            float2 y = Ys[g][n];
            accr[g] += ar * y.x + ai * y.y;   // conj(A)*Y
            acci[g] += ar * y.y - ai * y.x;
        }
    }
    float2* AY = (float2*)(ws + o_AY);
#pragma unroll
    for (int g = 0; g < 8; ++g) {
        AY[(size_t)(bb0 + g) * M_N + m] = make_float2(accr[g], acci[g]);
        ws[o_AYt + (size_t)m * B_N + (bb0 + g)] = accr[g];
        ws[o_AYt + 524288 + (size_t)m * B_N + (bb0 + g)] = acci[g];
    }
}

// ---------------- K2: conv1 (2->32, 3x3 SAME over [M=256, B=2048]) + ReLU ----------------
__global__ void k_conv1(const float* __restrict__ w1, const float* __restrict__ b1,
                        float* __restrict__ ws) {
    __shared__ float w1s[576], b1s[32];
    int tid = threadIdx.x;
    for (int i = tid; i < 576; i += 256) w1s[i] = w1[i];
    if (tid < 32) b1s[tid] = b1[tid];
    __syncthreads();
    int gidx = blockIdx.x * 256 + tid;
    int b = gidx & (B_N - 1), m = gidx >> 11;
    const float* xr = ws + o_AYt;
    float x[2][3][3];
#pragma unroll
    for (int c = 0; c < 2; ++c)
#pragma unroll
        for (int dm = 0; dm < 3; ++dm) {
            int mm = m + dm - 1;
#pragma unroll
            for (int db = 0; db < 3; ++db) {
                int bb = b + db - 1;
                x[c][dm][db] = (mm >= 0 && mm < M_N && bb >= 0 && bb < B_N)
                                 ? xr[(size_t)c * 524288 + (size_t)mm * B_N + bb] : 0.f;
            }
        }
    float* z1 = ws + o_z1;
    for (int oc = 0; oc < 32; ++oc) {
        float acc = b1s[oc];
#pragma unroll
        for (int c = 0; c < 2; ++c)
#pragma unroll
            for (int dm = 0; dm < 3; ++dm)
#pragma unroll
                for (int db = 0; db < 3; ++db)
                    acc += x[c][dm][db] * w1s[oc * 18 + c * 9 + dm * 3 + db];
        z1[(size_t)oc * 524288 + (size_t)m * B_N + b] = fmaxf(acc, 0.f);
    }
}

// ---------------- K3: conv2 (32->64, 3x3) + ReLU, partial sum over M-chunk ----------------
// grid 512 = 32 b-tiles(64 cols) x 16 m-chunks(16 rows). 256 thr = 16 bq(4b) x 16 oq(4oc).
__global__ void __launch_bounds__(256, 2)
k_conv2(const float* __restrict__ b2, float* __restrict__ ws) {
    __shared__ __align__(16) float zw[2][4][68];
    int tid = threadIdx.x;
    int bq = tid & 15, oq = tid >> 4;
    int bt = blockIdx.x & 31, mc = blockIdx.x >> 5;
    int b0 = bt * 64, mbase = mc * 16;
    const float* z1 = ws + o_z1;
    const float* w2t = ws + o_w2t;
    float bias[4];
#pragma unroll
    for (int o = 0; o < 4; ++o) bias[o] = b2[oq * 4 + o];
    float facc[4][4];
#pragma unroll
    for (int lb = 0; lb < 4; ++lb)
#pragma unroll
        for (int o = 0; o < 4; ++o) facc[lb][o] = 0.f;

    for (int ms = 0; ms < 8; ++ms) {
        int m0 = mbase + ms * 2;                 // output rows m0, m0+1; window m0-1..m0+2
        float acc[2][4][4];
#pragma unroll
        for (int tm = 0; tm < 2; ++tm)
#pragma unroll
            for (int lb = 0; lb < 4; ++lb)
#pragma unroll
                for (int o = 0; o < 4; ++o) acc[tm][lb][o] = bias[o];

        for (int icp = 0; icp < 16; ++icp) {
            for (int i = tid; i < 2 * 4 * 66; i += 256) {
                int icl = i / 264, rr = (i % 264) / 66, col = i % 66;
                int ic = icp * 2 + icl;
                int row = m0 - 1 + rr;
                int gb = b0 + col - 1;
                float v = 0.f;
                if (row >= 0 && row < M_N && gb >= 0 && gb < B_N)
                    v = z1[(size_t)ic * 524288 + (size_t)row * B_N + gb];
                zw[icl][rr][col] = v;
            }
            __syncthreads();
#pragma unroll
            for (int icl = 0; icl < 2; ++icl) {
                int ic = icp * 2 + icl;
                float wreg[9][4];
#pragma unroll
                for (int k = 0; k < 9; ++k) {
                    float4 w4 = *(const float4*)(w2t + ((size_t)ic * 9 + k) * 64 + oq * 4);
                    wreg[k][0] = w4.x; wreg[k][1] = w4.y; wreg[k][2] = w4.z; wreg[k][3] = w4.w;
                }
                float z[4][6];
#pragma unroll
                for (int r = 0; r < 4; ++r) {
                    float4 a4 = *(const float4*)&zw[icl][r][bq * 4];
                    float2 a2 = *(const float2*)&zw[icl][r][bq * 4 + 4];
                    z[r][0] = a4.x; z[r][1] = a4.y; z[r][2] = a4.z; z[r][3] = a4.w;
                    z[r][4] = a2.x; z[r][5] = a2.y;
                }
#pragma unroll
                for (int tm = 0; tm < 2; ++tm)
#pragma unroll
                    for (int dm = 0; dm < 3; ++dm)
#pragma unroll
                        for (int db = 0; db < 3; ++db) {
#pragma unroll
                            for (int lb = 0; lb < 4; ++lb)
#pragma unroll
                                for (int o = 0; o < 4; ++o)
                                    acc[tm][lb][o] += z[tm + dm][lb + db] * wreg[dm * 3 + db][o];
                        }
            }
            __syncthreads();
        }
#pragma unroll
        for (int tm = 0; tm < 2; ++tm)
#pragma unroll
            for (int lb = 0; lb < 4; ++lb)
#pragma unroll
                for (int o = 0; o < 4; ++o) facc[lb][o] += fmaxf(acc[tm][lb][o], 0.f);
    }
    float* fp = ws + o_fp + (size_t)mc * 131072;
#pragma unroll
    for (int o = 0; o < 4; ++o)
#pragma unroll
        for (int lb = 0; lb < 4; ++lb)
            fp[(size_t)(oq * 4 + o) * B_N + b0 + bq * 4 + lb] = facc[lb][o];
}

// ---------------- K3b: reduce partials -> f = mean over M ----------------
__global__ void k_fred(float* __restrict__ ws) {
    size_t i = (size_t)blockIdx.x * 256 + threadIdx.x;   // < 131072
    float s = 0.f;
    for (int p = 0; p < 16; ++p) s += ws[o_fp + (size_t)p * 131072 + i];
    ws[o_f + i] = s * (1.f / 256.f);
}

// ---------------- K4: c,d,T 1-D convs over batch axis (kernel 3 SAME) ----------------
__global__ void k_cdt(const float* __restrict__ hcw, const float* __restrict__ hcb,
                      const float* __restrict__ hdw, const float* __restrict__ hdb,
                      const float* __restrict__ hTw, const float* __restrict__ hTb,
                      float* __restrict__ ws, float* __restrict__ out) {
    int b = blockIdx.x * 256 + threadIdx.x;
    const float* f = ws + o_f;
    for (int l = 0; l < 9; ++l) {
        float acc = hcb[l];
        for (int ic = 0; ic < 64; ++ic)
#pragma unroll
            for (int k = 0; k < 3; ++k) {
                int bb = b + k - 1;
                if (bb >= 0 && bb < B_N) acc += f[(size_t)ic * B_N + bb] * hcw[l * 192 + ic * 3 + k];
            }
        float v = fminf(fmaxf(fabsf(acc), 1e-6f), 100.f);
        ws[o_c + (size_t)b * 9 + l] = v;
        if (b == B_N - 1) out[524288 + l] = v;
    }
    for (int l = 0; l < 9; ++l) {
        float acc = hdb[l];
        for (int ic = 0; ic < 64; ++ic)
#pragma unroll
            for (int k = 0; k < 3; ++k) {
                int bb = b + k - 1;
                if (bb >= 0 && bb < B_N) acc += f[(size_t)ic * B_N + bb] * hdw[l * 192 + ic * 3 + k];
            }
        float v = fmaxf(fabsf(acc), 1e-6f);                 // no upper clamp for d
        ws[o_dd + (size_t)b * 9 + l] = v;
        if (b == B_N - 1) out[524297 + l] = v;
    }
    for (int l = 0; l < 10; ++l) {
        float acc = hTb[l];
        for (int ic = 0; ic < 64; ++ic)
#pragma unroll
            for (int k = 0; k < 3; ++k) {
                int bb = b + k - 1;
                if (bb >= 0 && bb < B_N) acc += f[(size_t)ic * B_N + bb] * hTw[l * 192 + ic * 3 + k];
            }
        float v = fminf(fmaxf(fabsf(acc), 1e-6f), 100.f);
        ws[o_T + (size_t)b * 10 + l] = v;
        if (b == B_N - 1) out[524306 + l] = v;
    }
}

// ---------------- reduction helper: 24 simultaneous block sums ----------------
__device__ __forceinline__ void reduce24(float* v, float* red, int tid) {
#pragma unroll
    for (int i = 0; i < 24; ++i) {
        float x = v[i];
#pragma unroll
        for (int off = 32; off >= 1; off >>= 1) x += __shfl_xor(x, off, 64);
        v[i] = x;
    }
    int lane = tid & 63, wv = tid >> 6;
    __syncthreads();
    if (lane == 0) {
#pragma unroll
        for (int i = 0; i < 24; ++i) red[wv * 24 + i] = v[i];
    }
    __syncthreads();
#pragma unroll
    for (int i = 0; i < 24; ++i) v[i] = red[i] + red[24 + i] + red[48 + i] + red[72 + i];
}

// ---------------- K5: the 10-layer iteration, 8 batches per block ----------------
// eps1 = ||Y||^2 - 2 Re(AY^H U) + Re(U^H (AA U)); AA U reused as next layer's matvec.
__global__ void __launch_bounds__(256, 2)
k_iter(const float* __restrict__ a0p, const float* __restrict__ b0p, float* __restrict__ ws) {
    __shared__ __align__(16) float2 Us[M_N * 8];    // [j][g]
    __shared__ float red[96];
    int tid = threadIdx.x;
    int m = tid;
    int bb0 = blockIdx.x * 8;
    const float2* AA = (const float2*)(ws + o_AA);
    const float2* AY = (const float2*)(ws + o_AY);
    float a0 = a0p[0], b0v = b0p[0];
    float atot = a0 + (float)NM;
    float Dm = ws[o_D + m];
    float ayr[8], ayi[8], Ur[8], Ui[8], wr_[8], wi_[8], lam[8], eps[8], yn[8];
#pragma unroll
    for (int g = 0; g < 8; ++g) {
        float2 a = AY[(size_t)(bb0 + g) * M_N + m];
        ayr[g] = a.x; ayi[g] = a.y;
        Ur[g] = Ui[g] = wr_[g] = wi_[g] = 0.f;
        eps[g] = a0 / b0v;
        lam[g] = ws[o_c + (size_t)(bb0 + g) * 9] / ws[o_dd + (size_t)(bb0 + g) * 9];
        yn[g] = ws[o_yn + bb0 + g];
    }
    for (int k = 0; k < LNUM; ++k) {
#pragma unroll
        for (int g = 0; g < 8; ++g) {
            float Tk = ws[o_T + (size_t)(bb0 + g) * 10 + k];
            float inv = eps[g] / (eps[g] * Tk + lam[g] + EPS_Sf);
            float nr = Tk * Ur[g] - wr_[g] + ayr[g];
            float ni = Tk * Ui[g] - wi_[g] + ayi[g];
            Ur[g] = inv * nr;
            Ui[g] = inv * ni;
        }
        if (k == LNUM - 1) break;
#pragma unroll
        for (int g = 0; g < 8; ++g) Us[m * 8 + g] = make_float2(Ur[g], Ui[g]);
        __syncthreads();
#pragma unroll
        for (int g = 0; g < 8; ++g) { wr_[g] = 0.f; wi_[g] = 0.f; }
#pragma unroll 4
        for (int j = 0; j < M_N; ++j) {
            float2 a = AA[(size_t)j * M_N + m];   // conj(AA[j][m]) == AA[m][j] (Hermitian)
#pragma unroll
            for (int g = 0; g < 8; ++g) {
                float2 u = Us[j * 8 + g];
                wr_[g] += a.x * u.x + a.y * u.y;
                wi_[g] += a.x * u.y - a.y * u.x;
            }
        }
        float v[24], sig[8];
#pragma unroll
        for (int g = 0; g < 8; ++g) {
            sig[g] = 1.f / (eps[g] * Dm + lam[g] + EPS_Sf);
            v[g]      = ayr[g] * Ur[g] + ayi[g] * Ui[g];   // Re(conj(AY) U)
            v[8 + g]  = Ur[g] * wr_[g] + Ui[g] * wi_[g];   // Re(conj(U) w)
            v[16 + g] = Dm * sig[g];
        }
        reduce24(v, red, tid);
#pragma unroll
        for (int g = 0; g < 8; ++g) {
            float eps1 = yn[g] - 2.f * v[g] + v[8 + g];
            eps1 = fmaxf(eps1, 0.f);
            eps[g] = atot / (b0v + eps1 + v[16 + g] + EPS_Sf);
            float ck = ws[o_c + (size_t)(bb0 + g) * 9 + k];
            float dk = ws[o_dd + (size_t)(bb0 + g) * 9 + k];
            lam[g] = (ck + 1.f) / (dk + Ur[g] * Ur[g] + Ui[g] * Ui[g] + sig[g] + EPS_Sf);
        }
    }
    float localmax = 0.f;
#pragma unroll
    for (int g = 0; g < 8; ++g) {
        float ua = sqrtf(Ur[g] * Ur[g] + Ui[g] * Ui[g]);
        ws[o_Ua + (size_t)(bb0 + g) * M_N + m] = ua;
        localmax = fmaxf(localmax, ua);
    }
#pragma unroll
    for (int off = 32; off >= 1; off >>= 1) localmax = fmaxf(localmax, __shfl_xor(localmax, off, 64));
    __syncthreads();
    if ((tid & 63) == 0) red[tid >> 6] = localmax;
    __syncthreads();
    if (tid == 0) {
        float mx = fmaxf(fmaxf(red[0], red[1]), fmaxf(red[2], red[3]));
        atomicMax((unsigned int*)(ws + o_gm), __float_as_uint(mx));
    }
}

// ---------------- K6: normalize ----------------
__global__ void k_norm(const float* __restrict__ ws, float* __restrict__ out) {
    size_t i = (size_t)blockIdx.x * 256 + threadIdx.x;
    float gm = __uint_as_float(*(const unsigned int*)(ws + o_gm));
    out[i] = ws[o_Ua + i] / (gm + 1e-8f);
}

extern "C" void kernel_launch(void* const* d_in, const int* in_sizes, int n_in,
                              void* d_out, int out_size, void* d_ws, size_t ws_size,
                              hipStream_t stream) {
    (void)in_sizes; (void)n_in; (void)out_size; (void)ws_size;
    const float* Yr  = (const float*)d_in[0];
    const float* Yi  = (const float*)d_in[1];
    const float* Ar  = (const float*)d_in[2];
    const float* Ai  = (const float*)d_in[3];
    const float* w1  = (const float*)d_in[4];
    const float* b1  = (const float*)d_in[5];
    const float* w2  = (const float*)d_in[6];
    const float* b2  = (const float*)d_in[7];
    const float* hcw = (const float*)d_in[8];
    const float* hcb = (const float*)d_in[9];
    const float* hdw = (const float*)d_in[10];
    const float* hdb = (const float*)d_in[11];
    const float* hTw = (const float*)d_in[12];
    const float* hTb = (const float*)d_in[13];
    const float* a0  = (const float*)d_in[14];
    const float* b0  = (const float*)d_in[15];
    float* ws = (float*)d_ws;
    float* out = (float*)d_out;

    hipMemsetAsync((char*)d_ws + o_gm * sizeof(float), 0, 4, stream);
    k_aa   <<<256, 256, 0, stream>>>(Ar, Ai, ws);
    k_w2t  <<<72, 256, 0, stream>>>(w2, ws);
    k_ay   <<<256, 256, 0, stream>>>(Yr, Yi, Ar, Ai, ws);
    k_conv1<<<2048, 256, 0, stream>>>(w1, b1, ws);
    k_conv2<<<512, 256, 0, stream>>>(b2, ws);
    k_fred <<<512, 256, 0, stream>>>(ws);
    k_cdt  <<<8, 256, 0, stream>>>(hcw, hcb, hdw, hdb, hTw, hTb, ws, out);
    k_iter <<<256, 256, 0, stream>>>(a0, b0, ws);
    k_norm <<<2048, 256, 0, stream>>>(ws, out);
}

// Round 2
// 931.339 us; speedup vs baseline: 1.8238x; 1.8238x over previous
//
#include <hip/hip_runtime.h>
#include <math.h>

#define B_N   2048
#define NM    128
#define M_N   256
#define LNUM  10
#define EPS_Sf 1e-6f

// ---------------- workspace layout (float offsets) ----------------
static constexpr size_t o_AA  = 0;                       // float2[256*256] -> 131072 floats
static constexpr size_t o_D   = o_AA  + 131072;          // 256
static constexpr size_t o_yn  = o_D   + 256;             // 2048
static constexpr size_t o_AY  = o_yn  + 2048;            // float2[B*M] -> 1048576 floats
static constexpr size_t o_AYt = o_AY  + 1048576;         // [2][256][2048] = 1048576
static constexpr size_t o_w2t = o_AYt + 1048576;         // [ic][dm][db][oc] 18432
static constexpr size_t o_z1  = o_w2t + 18432;           // [32][256][2048] = 16777216
static constexpr size_t o_fp  = o_z1  + 16777216;        // [16][64][2048] = 2097152
static constexpr size_t o_f   = o_fp  + 2097152;         // [64][2048] = 131072
static constexpr size_t o_c   = o_f   + 131072;          // [2048][9]
static constexpr size_t o_dd  = o_c   + 18432;           // [2048][9]
static constexpr size_t o_T   = o_dd  + 18432;           // [2048][10]
static constexpr size_t o_Ua  = o_T   + 20480;           // 524288
static constexpr size_t o_gm  = o_Ua  + 524288;          // 1 (uint bits of max)

// ---------------- K0: AA = A^H A  (exactly Hermitian), D = diag ----------------
__global__ void k_aa(const float* __restrict__ Ar, const float* __restrict__ Ai,
                     float* __restrict__ ws) {
    __shared__ float cr[NM], ci[NM];
    int i = blockIdx.x, j = threadIdx.x;
    if (j < NM) { cr[j] = Ar[j * M_N + i]; ci[j] = Ai[j * M_N + i]; }
    __syncthreads();
    float sr = 0.f, si = 0.f;
    for (int n = 0; n < NM; ++n) {
        float ar = Ar[n * M_N + j], ai = Ai[n * M_N + j];
        sr += cr[n] * ar + ci[n] * ai;
        si += cr[n] * ai - ci[n] * ar;
    }
    float2* AA = (float2*)(ws + o_AA);
    AA[(size_t)i * M_N + j] = make_float2(sr, si);
    if (j == i) ws[o_D + i] = sr;
}

// ---------------- K0b: transpose conv2_w -> [ic][dm][db][oc] ----------------
__global__ void k_w2t(const float* __restrict__ w2, float* __restrict__ ws) {
    int i = blockIdx.x * 256 + threadIdx.x;
    if (i < 64 * 32 * 9) {
        int oc = i / 288, r = i % 288;
        int ic = r / 9, dm = (r % 9) / 3, db = r % 3;
        ws[o_w2t + ((size_t)((ic * 3 + dm) * 3 + db)) * 64 + oc] = w2[i];
    }
}

// ---------------- K1: AY = A^H Y, ||Y||^2, transposed layout for conv ----------------
__global__ void k_ay(const float* __restrict__ Yr, const float* __restrict__ Yi,
                     const float* __restrict__ Ar, const float* __restrict__ Ai,
                     float* __restrict__ ws) {
    __shared__ float2 Ys[8][NM];
    int bb0 = blockIdx.x * 8;
    int tid = threadIdx.x;
    for (int i = tid; i < 8 * NM; i += 256) {
        int g = i >> 7, n = i & 127;
        Ys[g][n] = make_float2(Yr[(size_t)(bb0 + g) * NM + n], Yi[(size_t)(bb0 + g) * NM + n]);
    }
    __syncthreads();
    if (tid < 8) {
        float s = 0.f;
        for (int n = 0; n < NM; ++n) { float2 y = Ys[tid][n]; s += y.x * y.x + y.y * y.y; }
        ws[o_yn + bb0 + tid] = s;
    }
    int m = tid;
    float accr[8], acci[8];
#pragma unroll
    for (int g = 0; g < 8; ++g) { accr[g] = 0.f; acci[g] = 0.f; }
    for (int n = 0; n < NM; ++n) {
        float ar = Ar[n * M_N + m], ai = Ai[n * M_N + m];
#pragma unroll
        for (int g = 0; g < 8; ++g) {
            float2 y = Ys[g][n];
            accr[g] += ar * y.x + ai * y.y;
            acci[g] += ar * y.y - ai * y.x;
        }
    }
    float2* AY = (float2*)(ws + o_AY);
#pragma unroll
    for (int g = 0; g < 8; ++g) {
        AY[(size_t)(bb0 + g) * M_N + m] = make_float2(accr[g], acci[g]);
        ws[o_AYt + (size_t)m * B_N + (bb0 + g)] = accr[g];
        ws[o_AYt + 524288 + (size_t)m * B_N + (bb0 + g)] = acci[g];
    }
}

// ---------------- K2: conv1 (2->32, 3x3 SAME over [M=256, B=2048]) + ReLU ----------------
__global__ void k_conv1(const float* __restrict__ w1, const float* __restrict__ b1,
                        float* __restrict__ ws) {
    __shared__ float w1s[576], b1s[32];
    int tid = threadIdx.x;
    for (int i = tid; i < 576; i += 256) w1s[i] = w1[i];
    if (tid < 32) b1s[tid] = b1[tid];
    __syncthreads();
    int gidx = blockIdx.x * 256 + tid;
    int b = gidx & (B_N - 1), m = gidx >> 11;
    const float* xr = ws + o_AYt;
    float x[2][3][3];
#pragma unroll
    for (int c = 0; c < 2; ++c)
#pragma unroll
        for (int dm = 0; dm < 3; ++dm) {
            int mm = m + dm - 1;
#pragma unroll
            for (int db = 0; db < 3; ++db) {
                int bb = b + db - 1;
                x[c][dm][db] = (mm >= 0 && mm < M_N && bb >= 0 && bb < B_N)
                                 ? xr[(size_t)c * 524288 + (size_t)mm * B_N + bb] : 0.f;
            }
        }
    float* z1 = ws + o_z1;
    for (int oc = 0; oc < 32; ++oc) {
        float acc = b1s[oc];
#pragma unroll
        for (int c = 0; c < 2; ++c)
#pragma unroll
            for (int dm = 0; dm < 3; ++dm)
#pragma unroll
                for (int db = 0; db < 3; ++db)
                    acc += x[c][dm][db] * w1s[oc * 18 + c * 9 + dm * 3 + db];
        z1[(size_t)oc * 524288 + (size_t)m * B_N + b] = fmaxf(acc, 0.f);
    }
}

// ---------------- K3: conv2 (32->64, 3x3) + ReLU, partial sum over M-chunk ----------------
// grid 1024 = 32 b-tiles(64 cols) x 16 m-chunks(16 rows) x 2 oc-halves(32 oc).
// 256 thr = 16 bq(4 b-cols) x 16 oq(2 oc). LDS: full 32-ic z tile + weight slice.
__global__ void __launch_bounds__(256, 2)
k_conv2(const float* __restrict__ b2, float* __restrict__ ws) {
    __shared__ float w2s[32][9][32];                 // 36 KB
    __shared__ __align__(16) float zw[32][4][68];    // 34.8 KB
    int tid = threadIdx.x;
    int bq = tid & 15, oq = tid >> 4;
    int blk = blockIdx.x;
    int bt = blk & 31, mc = (blk >> 5) & 15, og = blk >> 9;
    int b0 = bt * 64, mbase = mc * 16, oc0 = og * 32;
    const float* z1 = ws + o_z1;

    // stage weight slice [32 ic][9][32 oc]
    for (int i = tid; i < 32 * 9 * 32; i += 256) {
        int ic = i / 288, r = i % 288, k = r / 32, ocl = r & 31;
        w2s[ic][k][ocl] = ws[o_w2t + ((size_t)ic * 9 + k) * 64 + oc0 + ocl];
    }
    float bias0 = b2[oc0 + oq * 2], bias1 = b2[oc0 + oq * 2 + 1];

    // fill-role constants: lane = col (wave-coalesced), wave = row slot
    int col = tid & 63;
    int slot = tid >> 6;                 // 0..3, wave-uniform
    int gb = b0 - 1 + col;
    bool gok = (gb >= 0) && (gb < B_N);
    int gb2 = gb + 64;                   // only used when col < 4
    bool g2ok = (col < 4) && (gb2 < B_N);

    float facc[4][2];
#pragma unroll
    for (int lb = 0; lb < 4; ++lb) { facc[lb][0] = 0.f; facc[lb][1] = 0.f; }

    for (int ms = 0; ms < 8; ++ms) {
        int m0 = mbase + ms * 2;
        int row = m0 - 1 + slot;
        bool rok = (row >= 0) && (row < M_N);
        __syncthreads();                 // zw free to overwrite (also covers w2s staging)
        size_t base = (size_t)row * B_N;
        for (int ic = 0; ic < 32; ++ic) {
            float v0 = 0.f, v1 = 0.f;
            if (rok) {
                if (gok)  v0 = z1[(size_t)ic * 524288 + base + gb];
                if (g2ok) v1 = z1[(size_t)ic * 524288 + base + gb2];
            }
            zw[ic][slot][col] = v0;
            if (col < 4) zw[ic][slot][col + 64] = v1;
        }
        __syncthreads();

        float acc[2][4][2];
#pragma unroll
        for (int tm = 0; tm < 2; ++tm)
#pragma unroll
            for (int lb = 0; lb < 4; ++lb) { acc[tm][lb][0] = bias0; acc[tm][lb][1] = bias1; }

        for (int ic = 0; ic < 32; ++ic) {
            float2 wv[9];
#pragma unroll
            for (int k = 0; k < 9; ++k) wv[k] = *(const float2*)&w2s[ic][k][oq * 2];
            float z[4][6];
#pragma unroll
            for (int r = 0; r < 4; ++r) {
                float4 a4 = *(const float4*)&zw[ic][r][bq * 4];
                float2 a2 = *(const float2*)&zw[ic][r][bq * 4 + 4];
                z[r][0] = a4.x; z[r][1] = a4.y; z[r][2] = a4.z; z[r][3] = a4.w;
                z[r][4] = a2.x; z[r][5] = a2.y;
            }
#pragma unroll
            for (int tm = 0; tm < 2; ++tm)
#pragma unroll
                for (int dm = 0; dm < 3; ++dm)
#pragma unroll
                    for (int db = 0; db < 3; ++db) {
                        float2 w = wv[dm * 3 + db];
#pragma unroll
                        for (int lb = 0; lb < 4; ++lb) {
                            float zz = z[tm + dm][lb + db];
                            acc[tm][lb][0] += zz * w.x;
                            acc[tm][lb][1] += zz * w.y;
                        }
                    }
        }
#pragma unroll
        for (int tm = 0; tm < 2; ++tm)
#pragma unroll
            for (int lb = 0; lb < 4; ++lb) {
                facc[lb][0] += fmaxf(acc[tm][lb][0], 0.f);
                facc[lb][1] += fmaxf(acc[tm][lb][1], 0.f);
            }
    }
    float* fp = ws + o_fp + (size_t)mc * 131072;
#pragma unroll
    for (int o = 0; o < 2; ++o) {
        float4 v = make_float4(facc[0][o], facc[1][o], facc[2][o], facc[3][o]);
        *(float4*)&fp[(size_t)(oc0 + oq * 2 + o) * B_N + b0 + bq * 4] = v;
    }
}

// ---------------- K3b: reduce partials -> f = mean over M ----------------
__global__ void k_fred(float* __restrict__ ws) {
    size_t i = (size_t)blockIdx.x * 256 + threadIdx.x;
    float s = 0.f;
    for (int p = 0; p < 16; ++p) s += ws[o_fp + (size_t)p * 131072 + i];
    ws[o_f + i] = s * (1.f / 256.f);
}

// ---------------- K4: c,d,T 1-D convs over batch axis (kernel 3 SAME) ----------------
// grid 32 = 8 b-blocks x 4 l-groups {c0-8, d0-8, T0-4, T5-9}; f loads hoisted out of l-loop.
__global__ void k_cdt(const float* __restrict__ hcw, const float* __restrict__ hcb,
                      const float* __restrict__ hdw, const float* __restrict__ hdb,
                      const float* __restrict__ hTw, const float* __restrict__ hTb,
                      float* __restrict__ ws, float* __restrict__ out) {
    int b = (blockIdx.x & 7) * 256 + threadIdx.x;
    int grp = blockIdx.x >> 3;
    const float* f = ws + o_f;
    const float* w; const float* bi; int cnt, l0;
    if (grp == 0)      { w = hcw; bi = hcb; cnt = 9; l0 = 0; }
    else if (grp == 1) { w = hdw; bi = hdb; cnt = 9; l0 = 0; }
    else if (grp == 2) { w = hTw; bi = hTb; cnt = 5; l0 = 0; }
    else               { w = hTw; bi = hTb; cnt = 5; l0 = 5; }
    float acc[9];
    for (int i = 0; i < cnt; ++i) acc[i] = bi[l0 + i];
    bool okL = (b > 0), okR = (b < B_N - 1);
    for (int ic = 0; ic < 64; ++ic) {
        const float* fr = f + (size_t)ic * B_N + b;
        float fm1 = okL ? fr[-1] : 0.f;
        float f0  = fr[0];
        float fp1 = okR ? fr[1] : 0.f;
        for (int i = 0; i < cnt; ++i) {
            const float* wr = w + (size_t)(l0 + i) * 192 + ic * 3;
            acc[i] += fm1 * wr[0] + f0 * wr[1] + fp1 * wr[2];
        }
    }
    for (int i = 0; i < cnt; ++i) {
        float v = fmaxf(fabsf(acc[i]), 1e-6f);
        if (grp != 1) v = fminf(v, 100.f);
        int l = l0 + i;
        if (grp == 0)      { ws[o_c  + (size_t)b * 9  + l] = v; if (b == B_N - 1) out[524288 + l] = v; }
        else if (grp == 1) { ws[o_dd + (size_t)b * 9  + l] = v; if (b == B_N - 1) out[524297 + l] = v; }
        else               { ws[o_T  + (size_t)b * 10 + l] = v; if (b == B_N - 1) out[524306 + l] = v; }
    }
}

// ---------------- K5: 10-layer iteration. 512 thr: m=tid&255, tid>>8 splits 8 batches 4+4 ----
__global__ void __launch_bounds__(512, 2)
k_iter(const float* __restrict__ a0p, const float* __restrict__ b0p, float* __restrict__ ws) {
    __shared__ __align__(16) float2 Us[M_N][9];   // pad 8->9 float2: 4-way max bank alias
    __shared__ float red[8][12];
    __shared__ float redm[8];
    int tid = threadIdx.x;
    int m = tid & 255, h = tid >> 8;
    int wv = tid >> 6, lane = tid & 63;
    int bb0 = blockIdx.x * 8 + h * 4;
    const float2* AA = (const float2*)(ws + o_AA);
    const float2* AY = (const float2*)(ws + o_AY);
    float a0 = a0p[0], b0v = b0p[0];
    float atot = a0 + (float)NM;
    float Dm = ws[o_D + m];
    float ayr[4], ayi[4], Ur[4], Ui[4], wr_[4], wi_[4], lam[4], eps[4], yn[4];
#pragma unroll
    for (int g = 0; g < 4; ++g) {
        float2 a = AY[(size_t)(bb0 + g) * M_N + m];
        ayr[g] = a.x; ayi[g] = a.y;
        Ur[g] = Ui[g] = wr_[g] = wi_[g] = 0.f;
        eps[g] = a0 / b0v;
        lam[g] = ws[o_c + (size_t)(bb0 + g) * 9] / ws[o_dd + (size_t)(bb0 + g) * 9];
        yn[g] = ws[o_yn + bb0 + g];
    }
    for (int k = 0; k < LNUM; ++k) {
#pragma unroll
        for (int g = 0; g < 4; ++g) {
            float Tk = ws[o_T + (size_t)(bb0 + g) * 10 + k];
            float inv = eps[g] / (eps[g] * Tk + lam[g] + EPS_Sf);
            Ur[g] = inv * (Tk * Ur[g] - wr_[g] + ayr[g]);
            Ui[g] = inv * (Tk * Ui[g] - wi_[g] + ayi[g]);
        }
        if (k == LNUM - 1) break;
#pragma unroll
        for (int g = 0; g < 4; ++g) Us[m][h * 4 + g] = make_float2(Ur[g], Ui[g]);
        __syncthreads();
#pragma unroll
        for (int g = 0; g < 4; ++g) { wr_[g] = 0.f; wi_[g] = 0.f; }
#pragma unroll 8
        for (int j = 0; j < M_N; ++j) {
            float2 a = AA[(size_t)j * M_N + m];   // Hermitian: conj(AA[j][m]) = AA[m][j]
#pragma unroll
            for (int g = 0; g < 4; ++g) {
                float2 u = Us[j][h * 4 + g];
                wr_[g] += a.x * u.x + a.y * u.y;
                wi_[g] += a.x * u.y - a.y * u.x;
            }
        }
        float v[12], sig[4];
#pragma unroll
        for (int g = 0; g < 4; ++g) {
            sig[g] = 1.f / (eps[g] * Dm + lam[g] + EPS_Sf);
            v[g]     = ayr[g] * Ur[g] + ayi[g] * Ui[g];
            v[4 + g] = Ur[g] * wr_[g] + Ui[g] * wi_[g];
            v[8 + g] = Dm * sig[g];
        }
#pragma unroll
        for (int i = 0; i < 12; ++i) {
            float x = v[i];
#pragma unroll
            for (int off = 32; off >= 1; off >>= 1) x += __shfl_xor(x, off, 64);
            v[i] = x;
        }
        __syncthreads();
        if (lane == 0) {
#pragma unroll
            for (int i = 0; i < 12; ++i) red[wv][i] = v[i];
        }
        __syncthreads();
#pragma unroll
        for (int i = 0; i < 12; ++i)
            v[i] = red[h * 4][i] + red[h * 4 + 1][i] + red[h * 4 + 2][i] + red[h * 4 + 3][i];
#pragma unroll
        for (int g = 0; g < 4; ++g) {
            float eps1 = fmaxf(yn[g] - 2.f * v[g] + v[4 + g], 0.f);
            eps[g] = atot / (b0v + eps1 + v[8 + g] + EPS_Sf);
            float ck = ws[o_c + (size_t)(bb0 + g) * 9 + k];
            float dk = ws[o_dd + (size_t)(bb0 + g) * 9 + k];
            lam[g] = (ck + 1.f) / (dk + Ur[g] * Ur[g] + Ui[g] * Ui[g] + sig[g] + EPS_Sf);
        }
    }
    float localmax = 0.f;
#pragma unroll
    for (int g = 0; g < 4; ++g) {
        float ua = sqrtf(Ur[g] * Ur[g] + Ui[g] * Ui[g]);
        ws[o_Ua + (size_t)(bb0 + g) * M_N + m] = ua;
        localmax = fmaxf(localmax, ua);
    }
#pragma unroll
    for (int off = 32; off >= 1; off >>= 1) localmax = fmaxf(localmax, __shfl_xor(localmax, off, 64));
    __syncthreads();
    if (lane == 0) redm[wv] = localmax;
    __syncthreads();
    if (tid == 0) {
        float mx = redm[0];
#pragma unroll
        for (int i = 1; i < 8; ++i) mx = fmaxf(mx, redm[i]);
        atomicMax((unsigned int*)(ws + o_gm), __float_as_uint(mx));
    }
}

// ---------------- K6: normalize ----------------
__global__ void k_norm(const float* __restrict__ ws, float* __restrict__ out) {
    size_t i = (size_t)blockIdx.x * 256 + threadIdx.x;
    float gm = __uint_as_float(*(const unsigned int*)(ws + o_gm));
    out[i] = ws[o_Ua + i] / (gm + 1e-8f);
}

extern "C" void kernel_launch(void* const* d_in, const int* in_sizes, int n_in,
                              void* d_out, int out_size, void* d_ws, size_t ws_size,
                              hipStream_t stream) {
    (void)in_sizes; (void)n_in; (void)out_size; (void)ws_size;
    const float* Yr  = (const float*)d_in[0];
    const float* Yi  = (const float*)d_in[1];
    const float* Ar  = (const float*)d_in[2];
    const float* Ai  = (const float*)d_in[3];
    const float* w1  = (const float*)d_in[4];
    const float* b1  = (const float*)d_in[5];
    const float* w2  = (const float*)d_in[6];
    const float* b2  = (const float*)d_in[7];
    const float* hcw = (const float*)d_in[8];
    const float* hcb = (const float*)d_in[9];
    const float* hdw = (const float*)d_in[10];
    const float* hdb = (const float*)d_in[11];
    const float* hTw = (const float*)d_in[12];
    const float* hTb = (const float*)d_in[13];
    const float* a0  = (const float*)d_in[14];
    const float* b0  = (const float*)d_in[15];
    float* ws = (float*)d_ws;
    float* out = (float*)d_out;

    hipMemsetAsync((char*)d_ws + o_gm * sizeof(float), 0, 4, stream);
    k_aa   <<<256, 256, 0, stream>>>(Ar, Ai, ws);
    k_w2t  <<<72, 256, 0, stream>>>(w2, ws);
    k_ay   <<<256, 256, 0, stream>>>(Yr, Yi, Ar, Ai, ws);
    k_conv1<<<2048, 256, 0, stream>>>(w1, b1, ws);
    k_conv2<<<1024, 256, 0, stream>>>(b2, ws);
    k_fred <<<512, 256, 0, stream>>>(ws);
    k_cdt  <<<32, 256, 0, stream>>>(hcw, hcb, hdw, hdb, hTw, hTb, ws, out);
    k_iter <<<256, 512, 0, stream>>>(a0, b0, ws);
    k_norm <<<2048, 256, 0, stream>>>(ws, out);
}

// Round 3
// 700.996 us; speedup vs baseline: 2.4231x; 1.3286x over previous
//
#include <hip/hip_runtime.h>
#include <math.h>

#define B_N   2048
#define NM    128
#define M_N   256
#define LNUM  10
#define EPS_Sf 1e-6f

typedef _Float16 half8 __attribute__((ext_vector_type(8)));
typedef float floatx4 __attribute__((ext_vector_type(4)));

// ---------------- workspace layout (float offsets) ----------------
// o_AA region now holds 4 f16 matrices 256x256: [AAr_hi|AAr_lo|AAi_hi|AAi_lo]
static constexpr size_t o_AA  = 0;                       // 4*65536 f16 = 131072 floats
static constexpr size_t o_D   = o_AA  + 131072;          // 256
static constexpr size_t o_yn  = o_D   + 256;             // 2048
static constexpr size_t o_AY  = o_yn  + 2048;            // float2[B*M] -> 1048576 floats
static constexpr size_t o_AYt = o_AY  + 1048576;         // [2][256][2048] = 1048576
static constexpr size_t o_w2t = o_AYt + 1048576;         // [ic][dm][db][oc] 18432
static constexpr size_t o_z1  = o_w2t + 18432;           // [32][256][2048] = 16777216
static constexpr size_t o_fp  = o_z1  + 16777216;        // [16][64][2048] = 2097152
static constexpr size_t o_f   = o_fp  + 2097152;         // [64][2048] = 131072
static constexpr size_t o_c   = o_f   + 131072;          // [2048][9]
static constexpr size_t o_dd  = o_c   + 18432;           // [2048][9]
static constexpr size_t o_T   = o_dd  + 18432;           // [2048][10]
static constexpr size_t o_Ua  = o_T   + 20480;           // 524288
static constexpr size_t o_gm  = o_Ua  + 524288;          // 1 (uint bits of max)

__device__ __forceinline__ void split2(float x, _Float16& h, _Float16& l) {
    h = (_Float16)x;
    l = (_Float16)(x - (float)h);
}

// ---------------- K0: AA = A^H A, stored as f16 hi/lo planes; D = diag ----------------
__global__ void k_aa(const float* __restrict__ Ar, const float* __restrict__ Ai,
                     float* __restrict__ ws) {
    __shared__ float cr[NM], ci[NM];
    int i = blockIdx.x, j = threadIdx.x;
    if (j < NM) { cr[j] = Ar[j * M_N + i]; ci[j] = Ai[j * M_N + i]; }
    __syncthreads();
    float sr = 0.f, si = 0.f;
    for (int n = 0; n < NM; ++n) {
        float ar = Ar[n * M_N + j], ai = Ai[n * M_N + j];
        sr += cr[n] * ar + ci[n] * ai;   // Re AA(i,j)
        si += cr[n] * ai - ci[n] * ar;   // Im AA(i,j)
    }
    _Float16* A16 = (_Float16*)(ws + o_AA);
    size_t off = (size_t)i * M_N + j;    // row-major [m=i][j]
    _Float16 h, l;
    split2(sr, h, l); A16[off] = h;          A16[65536 + off]  = l;
    split2(si, h, l); A16[131072 + off] = h; A16[196608 + off] = l;
    if (j == i) ws[o_D + i] = sr;
}

// ---------------- K0b: transpose conv2_w -> [ic][dm][db][oc] ----------------
__global__ void k_w2t(const float* __restrict__ w2, float* __restrict__ ws) {
    int i = blockIdx.x * 256 + threadIdx.x;
    if (i < 64 * 32 * 9) {
        int oc = i / 288, r = i % 288;
        int ic = r / 9, dm = (r % 9) / 3, db = r % 3;
        ws[o_w2t + ((size_t)((ic * 3 + dm) * 3 + db)) * 64 + oc] = w2[i];
    }
}

// ---------------- K1: AY = A^H Y, ||Y||^2, transposed layout for conv ----------------
__global__ void k_ay(const float* __restrict__ Yr, const float* __restrict__ Yi,
                     const float* __restrict__ Ar, const float* __restrict__ Ai,
                     float* __restrict__ ws) {
    __shared__ float2 Ys[8][NM];
    int bb0 = blockIdx.x * 8;
    int tid = threadIdx.x;
    for (int i = tid; i < 8 * NM; i += 256) {
        int g = i >> 7, n = i & 127;
        Ys[g][n] = make_float2(Yr[(size_t)(bb0 + g) * NM + n], Yi[(size_t)(bb0 + g) * NM + n]);
    }
    __syncthreads();
    if (tid < 8) {
        float s = 0.f;
        for (int n = 0; n < NM; ++n) { float2 y = Ys[tid][n]; s += y.x * y.x + y.y * y.y; }
        ws[o_yn + bb0 + tid] = s;
    }
    int m = tid;
    float accr[8], acci[8];
#pragma unroll
    for (int g = 0; g < 8; ++g) { accr[g] = 0.f; acci[g] = 0.f; }
    for (int n = 0; n < NM; ++n) {
        float ar = Ar[n * M_N + m], ai = Ai[n * M_N + m];
#pragma unroll
        for (int g = 0; g < 8; ++g) {
            float2 y = Ys[g][n];
            accr[g] += ar * y.x + ai * y.y;
            acci[g] += ar * y.y - ai * y.x;
        }
    }
    float2* AY = (float2*)(ws + o_AY);
#pragma unroll
    for (int g = 0; g < 8; ++g) {
        AY[(size_t)(bb0 + g) * M_N + m] = make_float2(accr[g], acci[g]);
        ws[o_AYt + (size_t)m * B_N + (bb0 + g)] = accr[g];
        ws[o_AYt + 524288 + (size_t)m * B_N + (bb0 + g)] = acci[g];
    }
}

// ---------------- K2: conv1 (2->32, 3x3 SAME over [M=256, B=2048]) + ReLU ----------------
__global__ void k_conv1(const float* __restrict__ w1, const float* __restrict__ b1,
                        float* __restrict__ ws) {
    __shared__ float w1s[576], b1s[32];
    int tid = threadIdx.x;
    for (int i = tid; i < 576; i += 256) w1s[i] = w1[i];
    if (tid < 32) b1s[tid] = b1[tid];
    __syncthreads();
    int gidx = blockIdx.x * 256 + tid;
    int b = gidx & (B_N - 1), m = gidx >> 11;
    const float* xr = ws + o_AYt;
    float x[2][3][3];
#pragma unroll
    for (int c = 0; c < 2; ++c)
#pragma unroll
        for (int dm = 0; dm < 3; ++dm) {
            int mm = m + dm - 1;
#pragma unroll
            for (int db = 0; db < 3; ++db) {
                int bb = b + db - 1;
                x[c][dm][db] = (mm >= 0 && mm < M_N && bb >= 0 && bb < B_N)
                                 ? xr[(size_t)c * 524288 + (size_t)mm * B_N + bb] : 0.f;
            }
        }
    float* z1 = ws + o_z1;
    for (int oc = 0; oc < 32; ++oc) {
        float acc = b1s[oc];
#pragma unroll
        for (int c = 0; c < 2; ++c)
#pragma unroll
            for (int dm = 0; dm < 3; ++dm)
#pragma unroll
                for (int db = 0; db < 3; ++db)
                    acc += x[c][dm][db] * w1s[oc * 18 + c * 9 + dm * 3 + db];
        z1[(size_t)oc * 524288 + (size_t)m * B_N + b] = fmaxf(acc, 0.f);
    }
}

// ---------------- K3: conv2 (32->64, 3x3) + ReLU, partial sum over M-chunk ----------------
__global__ void __launch_bounds__(256, 2)
k_conv2(const float* __restrict__ b2, float* __restrict__ ws) {
    __shared__ float w2s[32][9][32];
    __shared__ __align__(16) float zw[32][4][68];
    int tid = threadIdx.x;
    int bq = tid & 15, oq = tid >> 4;
    int blk = blockIdx.x;
    int bt = blk & 31, mc = (blk >> 5) & 15, og = blk >> 9;
    int b0 = bt * 64, mbase = mc * 16, oc0 = og * 32;
    const float* z1 = ws + o_z1;

    for (int i = tid; i < 32 * 9 * 32; i += 256) {
        int ic = i / 288, r = i % 288, k = r / 32, ocl = r & 31;
        w2s[ic][k][ocl] = ws[o_w2t + ((size_t)ic * 9 + k) * 64 + oc0 + ocl];
    }
    float bias0 = b2[oc0 + oq * 2], bias1 = b2[oc0 + oq * 2 + 1];

    int col = tid & 63;
    int slot = tid >> 6;
    int gb = b0 - 1 + col;
    bool gok = (gb >= 0) && (gb < B_N);
    int gb2 = gb + 64;
    bool g2ok = (col < 4) && (gb2 < B_N);

    float facc[4][2];
#pragma unroll
    for (int lb = 0; lb < 4; ++lb) { facc[lb][0] = 0.f; facc[lb][1] = 0.f; }

    for (int ms = 0; ms < 8; ++ms) {
        int m0 = mbase + ms * 2;
        int row = m0 - 1 + slot;
        bool rok = (row >= 0) && (row < M_N);
        __syncthreads();
        size_t base = (size_t)row * B_N;
        for (int ic = 0; ic < 32; ++ic) {
            float v0 = 0.f, v1 = 0.f;
            if (rok) {
                if (gok)  v0 = z1[(size_t)ic * 524288 + base + gb];
                if (g2ok) v1 = z1[(size_t)ic * 524288 + base + gb2];
            }
            zw[ic][slot][col] = v0;
            if (col < 4) zw[ic][slot][col + 64] = v1;
        }
        __syncthreads();

        float acc[2][4][2];
#pragma unroll
        for (int tm = 0; tm < 2; ++tm)
#pragma unroll
            for (int lb = 0; lb < 4; ++lb) { acc[tm][lb][0] = bias0; acc[tm][lb][1] = bias1; }

        for (int ic = 0; ic < 32; ++ic) {
            float2 wv[9];
#pragma unroll
            for (int k = 0; k < 9; ++k) wv[k] = *(const float2*)&w2s[ic][k][oq * 2];
            float z[4][6];
#pragma unroll
            for (int r = 0; r < 4; ++r) {
                float4 a4 = *(const float4*)&zw[ic][r][bq * 4];
                float2 a2 = *(const float2*)&zw[ic][r][bq * 4 + 4];
                z[r][0] = a4.x; z[r][1] = a4.y; z[r][2] = a4.z; z[r][3] = a4.w;
                z[r][4] = a2.x; z[r][5] = a2.y;
            }
#pragma unroll
            for (int tm = 0; tm < 2; ++tm)
#pragma unroll
                for (int dm = 0; dm < 3; ++dm)
#pragma unroll
                    for (int db = 0; db < 3; ++db) {
                        float2 w = wv[dm * 3 + db];
#pragma unroll
                        for (int lb = 0; lb < 4; ++lb) {
                            float zz = z[tm + dm][lb + db];
                            acc[tm][lb][0] += zz * w.x;
                            acc[tm][lb][1] += zz * w.y;
                        }
                    }
        }
#pragma unroll
        for (int tm = 0; tm < 2; ++tm)
#pragma unroll
            for (int lb = 0; lb < 4; ++lb) {
                facc[lb][0] += fmaxf(acc[tm][lb][0], 0.f);
                facc[lb][1] += fmaxf(acc[tm][lb][1], 0.f);
            }
    }
    float* fp = ws + o_fp + (size_t)mc * 131072;
#pragma unroll
    for (int o = 0; o < 2; ++o) {
        float4 v = make_float4(facc[0][o], facc[1][o], facc[2][o], facc[3][o]);
        *(float4*)&fp[(size_t)(oc0 + oq * 2 + o) * B_N + b0 + bq * 4] = v;
    }
}

// ---------------- K3b: reduce partials -> f = mean over M ----------------
__global__ void k_fred(float* __restrict__ ws) {
    size_t i = (size_t)blockIdx.x * 256 + threadIdx.x;
    float s = 0.f;
    for (int p = 0; p < 16; ++p) s += ws[o_fp + (size_t)p * 131072 + i];
    ws[o_f + i] = s * (1.f / 256.f);
}

// ---------------- K4: c,d,T 1-D convs over batch axis ----------------
__global__ void k_cdt(const float* __restrict__ hcw, const float* __restrict__ hcb,
                      const float* __restrict__ hdw, const float* __restrict__ hdb,
                      const float* __restrict__ hTw, const float* __restrict__ hTb,
                      float* __restrict__ ws, float* __restrict__ out) {
    int b = (blockIdx.x & 7) * 256 + threadIdx.x;
    int grp = blockIdx.x >> 3;
    const float* f = ws + o_f;
    const float* w; const float* bi; int cnt, l0;
    if (grp == 0)      { w = hcw; bi = hcb; cnt = 9; l0 = 0; }
    else if (grp == 1) { w = hdw; bi = hdb; cnt = 9; l0 = 0; }
    else if (grp == 2) { w = hTw; bi = hTb; cnt = 5; l0 = 0; }
    else               { w = hTw; bi = hTb; cnt = 5; l0 = 5; }
    float acc[9];
    for (int i = 0; i < cnt; ++i) acc[i] = bi[l0 + i];
    bool okL = (b > 0), okR = (b < B_N - 1);
    for (int ic = 0; ic < 64; ++ic) {
        const float* fr = f + (size_t)ic * B_N + b;
        float fm1 = okL ? fr[-1] : 0.f;
        float f0  = fr[0];
        float fp1 = okR ? fr[1] : 0.f;
        for (int i = 0; i < cnt; ++i) {
            const float* wr = w + (size_t)(l0 + i) * 192 + ic * 3;
            acc[i] += fm1 * wr[0] + f0 * wr[1] + fp1 * wr[2];
        }
    }
    for (int i = 0; i < cnt; ++i) {
        float v = fmaxf(fabsf(acc[i]), 1e-6f);
        if (grp != 1) v = fminf(v, 100.f);
        int l = l0 + i;
        if (grp == 0)      { ws[o_c  + (size_t)b * 9  + l] = v; if (b == B_N - 1) out[524288 + l] = v; }
        else if (grp == 1) { ws[o_dd + (size_t)b * 9  + l] = v; if (b == B_N - 1) out[524297 + l] = v; }
        else               { ws[o_T  + (size_t)b * 10 + l] = v; if (b == B_N - 1) out[524306 + l] = v; }
    }
}

// ---------------- K5: 10-layer iteration via f16x3 MFMA ----------------
// Block: 16 batches x full m=256. 512 thr = 8 waves, wave w owns m rows [w*32, w*32+32)
// as 2 MFMA row-tiles. C layout: col=lane&15 -> batch, row=quad*4+reg -> m.
// GEMM per layer: w[m][b] = AAr*ur - AAi*ui ; AAi sign folded via negated ui comps.
#define MFMA16(A,Bv,C) C = __builtin_amdgcn_mfma_f32_16x16x32_f16(A, Bv, C, 0, 0, 0)
__global__ void __launch_bounds__(512, 2)
k_iter(const float* __restrict__ a0p, const float* __restrict__ b0p, float* __restrict__ ws) {
    __shared__ __align__(16) _Float16 Ub[6][16][264];  // comps: urh,url,uih,uil,-uih,-uil
    __shared__ float redv[8][16][3];
    __shared__ float redm[8];
    int tid = threadIdx.x;
    int lane = tid & 63, w = tid >> 6;
    int col = lane & 15, quad = lane >> 4;
    int bb0 = blockIdx.x * 16;
    int b = bb0 + col;
    const float2* AY = (const float2*)(ws + o_AY);
    const _Float16* Arh = (const _Float16*)(ws + o_AA);
    const _Float16* Arl = Arh + 65536;
    const _Float16* Aih = Arh + 131072;
    const _Float16* Ail = Arh + 196608;
    float a0 = a0p[0], b0v = b0p[0];
    float atot = a0 + (float)NM;
    float yn = ws[o_yn + b];
    float eps = a0 / b0v;
    float lam0 = ws[o_c + (size_t)b * 9] / ws[o_dd + (size_t)b * 9];
    float Dv[2][4], ayr[2][4], ayi[2][4], lam[2][4], Ur[2][4], Ui[2][4], sg[2][4];
    floatx4 wr[2], wi[2];
#pragma unroll
    for (int t = 0; t < 2; ++t) {
        wr[t] = (floatx4){0.f, 0.f, 0.f, 0.f};
        wi[t] = (floatx4){0.f, 0.f, 0.f, 0.f};
#pragma unroll
        for (int r = 0; r < 4; ++r) {
            int m = w * 32 + t * 16 + quad * 4 + r;
            Dv[t][r] = ws[o_D + m];
            float2 a = AY[(size_t)b * M_N + m];
            ayr[t][r] = a.x; ayi[t][r] = a.y;
            lam[t][r] = lam0;
            Ur[t][r] = 0.f; Ui[t][r] = 0.f;
        }
    }
    for (int k = 0; k < LNUM; ++k) {
        float Tk = ws[o_T + (size_t)b * 10 + k];
#pragma unroll
        for (int t = 0; t < 2; ++t)
#pragma unroll
            for (int r = 0; r < 4; ++r) {
                float iv = eps / (eps * Tk + lam[t][r] + EPS_Sf);
                Ur[t][r] = iv * (Tk * Ur[t][r] - wr[t][r] + ayr[t][r]);
                Ui[t][r] = iv * (Tk * Ui[t][r] - wi[t][r] + ayi[t][r]);
            }
        if (k == LNUM - 1) break;
        // ---- stage U comps to LDS (safe: all waves passed the redv barrier) ----
#pragma unroll
        for (int t = 0; t < 2; ++t) {
            int j0 = w * 32 + t * 16 + quad * 4;
            _Float16 rh[4], rl[4], ih[4], il[4];
#pragma unroll
            for (int r = 0; r < 4; ++r) {
                split2(Ur[t][r], rh[r], rl[r]);
                split2(Ui[t][r], ih[r], il[r]);
            }
            _Float16* bp = &Ub[0][col][j0];
#pragma unroll
            for (int c2 = 0; c2 < 6; ++c2) {
                _Float16 h0, h1, h2, h3;
                if (c2 == 0)      { h0 = rh[0]; h1 = rh[1]; h2 = rh[2]; h3 = rh[3]; }
                else if (c2 == 1) { h0 = rl[0]; h1 = rl[1]; h2 = rl[2]; h3 = rl[3]; }
                else if (c2 == 2) { h0 = ih[0]; h1 = ih[1]; h2 = ih[2]; h3 = ih[3]; }
                else if (c2 == 3) { h0 = il[0]; h1 = il[1]; h2 = il[2]; h3 = il[3]; }
                else if (c2 == 4) { h0 = -ih[0]; h1 = -ih[1]; h2 = -ih[2]; h3 = -ih[3]; }
                else              { h0 = -il[0]; h1 = -il[1]; h2 = -il[2]; h3 = -il[3]; }
                union { _Float16 h[2]; unsigned u; } p0, p1;
                p0.h[0] = h0; p0.h[1] = h1; p1.h[0] = h2; p1.h[1] = h3;
                *(unsigned*)(bp + (size_t)c2 * 4224)     = p0.u;
                *(unsigned*)(bp + (size_t)c2 * 4224 + 2) = p1.u;
            }
        }
        __syncthreads();
        // ---- GEMM: w = AA * U  (f16x3, complex) ----
        wr[0] = (floatx4){0.f, 0.f, 0.f, 0.f}; wi[0] = (floatx4){0.f, 0.f, 0.f, 0.f};
        wr[1] = (floatx4){0.f, 0.f, 0.f, 0.f}; wi[1] = (floatx4){0.f, 0.f, 0.f, 0.f};
        for (int ks = 0; ks < 8; ++ks) {
            int j0 = ks * 32 + quad * 8;
            const _Float16* ub = &Ub[0][col][j0];
            half8 urh = *(const half8*)(ub);
            half8 url = *(const half8*)(ub + 4224);
            half8 uih = *(const half8*)(ub + 2 * 4224);
            half8 uil = *(const half8*)(ub + 3 * 4224);
            half8 nih = *(const half8*)(ub + 4 * 4224);
            half8 nil_ = *(const half8*)(ub + 5 * 4224);
#pragma unroll
            for (int t = 0; t < 2; ++t) {
                size_t ao = (size_t)(w * 32 + t * 16 + col) * M_N + j0;
                half8 arh = *(const half8*)(Arh + ao);
                half8 arl = *(const half8*)(Arl + ao);
                half8 aih = *(const half8*)(Aih + ao);
                half8 ail = *(const half8*)(Ail + ao);
                MFMA16(arh, urh, wr[t]);
                MFMA16(arh, url, wr[t]);
                MFMA16(arl, urh, wr[t]);
                MFMA16(aih, nih, wr[t]);
                MFMA16(aih, nil_, wr[t]);
                MFMA16(ail, nih, wr[t]);
                MFMA16(arh, uih, wi[t]);
                MFMA16(arh, uil, wi[t]);
                MFMA16(arl, uih, wi[t]);
                MFMA16(aih, urh, wi[t]);
                MFMA16(aih, url, wi[t]);
                MFMA16(ail, urh, wi[t]);
            }
        }
        // ---- per-batch reductions over m ----
        float p1 = 0.f, p2 = 0.f, p3 = 0.f;
#pragma unroll
        for (int t = 0; t < 2; ++t)
#pragma unroll
            for (int r = 0; r < 4; ++r) {
                sg[t][r] = 1.f / (eps * Dv[t][r] + lam[t][r] + EPS_Sf);
                p1 += ayr[t][r] * Ur[t][r] + ayi[t][r] * Ui[t][r];
                p2 += Ur[t][r] * wr[t][r] + Ui[t][r] * wi[t][r];
                p3 += Dv[t][r] * sg[t][r];
            }
        p1 += __shfl_xor(p1, 16); p1 += __shfl_xor(p1, 32);
        p2 += __shfl_xor(p2, 16); p2 += __shfl_xor(p2, 32);
        p3 += __shfl_xor(p3, 16); p3 += __shfl_xor(p3, 32);
        if (lane < 16) { redv[w][col][0] = p1; redv[w][col][1] = p2; redv[w][col][2] = p3; }
        __syncthreads();
        float s1 = 0.f, s2 = 0.f, s3 = 0.f;
#pragma unroll
        for (int u8 = 0; u8 < 8; ++u8) {
            s1 += redv[u8][col][0]; s2 += redv[u8][col][1]; s3 += redv[u8][col][2];
        }
        float eps1 = fmaxf(yn - 2.f * s1 + s2, 0.f);
        eps = atot / (b0v + eps1 + s3 + EPS_Sf);
        float ck = ws[o_c + (size_t)b * 9 + k];
        float dk = ws[o_dd + (size_t)b * 9 + k];
#pragma unroll
        for (int t = 0; t < 2; ++t)
#pragma unroll
            for (int r = 0; r < 4; ++r)
                lam[t][r] = (ck + 1.f) / (dk + Ur[t][r] * Ur[t][r] + Ui[t][r] * Ui[t][r]
                                          + sg[t][r] + EPS_Sf);
    }
    // ---- |U|, global max ----
    float lm = 0.f;
#pragma unroll
    for (int t = 0; t < 2; ++t) {
        float4 v;
        v.x = sqrtf(Ur[t][0] * Ur[t][0] + Ui[t][0] * Ui[t][0]);
        v.y = sqrtf(Ur[t][1] * Ur[t][1] + Ui[t][1] * Ui[t][1]);
        v.z = sqrtf(Ur[t][2] * Ur[t][2] + Ui[t][2] * Ui[t][2]);
        v.w = sqrtf(Ur[t][3] * Ur[t][3] + Ui[t][3] * Ui[t][3]);
        lm = fmaxf(lm, fmaxf(fmaxf(v.x, v.y), fmaxf(v.z, v.w)));
        *(float4*)&ws[o_Ua + (size_t)b * M_N + w * 32 + t * 16 + quad * 4] = v;
    }
#pragma unroll
    for (int off = 32; off >= 1; off >>= 1) lm = fmaxf(lm, __shfl_xor(lm, off));
    if (lane == 0) redm[w] = lm;
    __syncthreads();
    if (tid == 0) {
        float mx = redm[0];
#pragma unroll
        for (int i = 1; i < 8; ++i) mx = fmaxf(mx, redm[i]);
        atomicMax((unsigned int*)(ws + o_gm), __float_as_uint(mx));
    }
}

// ---------------- K6: normalize ----------------
__global__ void k_norm(const float* __restrict__ ws, float* __restrict__ out) {
    size_t i = (size_t)blockIdx.x * 256 + threadIdx.x;
    float gm = __uint_as_float(*(const unsigned int*)(ws + o_gm));
    out[i] = ws[o_Ua + i] / (gm + 1e-8f);
}

extern "C" void kernel_launch(void* const* d_in, const int* in_sizes, int n_in,
                              void* d_out, int out_size, void* d_ws, size_t ws_size,
                              hipStream_t stream) {
    (void)in_sizes; (void)n_in; (void)out_size; (void)ws_size;
    const float* Yr  = (const float*)d_in[0];
    const float* Yi  = (const float*)d_in[1];
    const float* Ar  = (const float*)d_in[2];
    const float* Ai  = (const float*)d_in[3];
    const float* w1  = (const float*)d_in[4];
    const float* b1  = (const float*)d_in[5];
    const float* w2  = (const float*)d_in[6];
    const float* b2  = (const float*)d_in[7];
    const float* hcw = (const float*)d_in[8];
    const float* hcb = (const float*)d_in[9];
    const float* hdw = (const float*)d_in[10];
    const float* hdb = (const float*)d_in[11];
    const float* hTw = (const float*)d_in[12];
    const float* hTb = (const float*)d_in[13];
    const float* a0  = (const float*)d_in[14];
    const float* b0  = (const float*)d_in[15];
    float* ws = (float*)d_ws;
    float* out = (float*)d_out;

    hipMemsetAsync((char*)d_ws + o_gm * sizeof(float), 0, 4, stream);
    k_aa   <<<256, 256, 0, stream>>>(Ar, Ai, ws);
    k_w2t  <<<72, 256, 0, stream>>>(w2, ws);
    k_ay   <<<256, 256, 0, stream>>>(Yr, Yi, Ar, Ai, ws);
    k_conv1<<<2048, 256, 0, stream>>>(w1, b1, ws);
    k_conv2<<<1024, 256, 0, stream>>>(b2, ws);
    k_fred <<<512, 256, 0, stream>>>(ws);
    k_cdt  <<<32, 256, 0, stream>>>(hcw, hcb, hdw, hdb, hTw, hTb, ws, out);
    k_iter <<<128, 512, 0, stream>>>(a0, b0, ws);
    k_norm <<<2048, 256, 0, stream>>>(ws, out);
}

// Round 4
// 400.546 us; speedup vs baseline: 4.2406x; 1.7501x over previous
//
#include <hip/hip_runtime.h>
#include <math.h>

#define B_N   2048
#define NM    128
#define M_N   256
#define LNUM  10
#define EPS_Sf 1e-6f

typedef _Float16 half8 __attribute__((ext_vector_type(8)));
typedef float floatx4 __attribute__((ext_vector_type(4)));

// ---------------- workspace layout (float offsets) ----------------
// o_AA region holds 4 f16 matrices 256x256: [AAr_hi|AAr_lo|AAi_hi|AAi_lo]
static constexpr size_t o_AA  = 0;                       // 4*65536 f16 = 131072 floats
static constexpr size_t o_D   = o_AA  + 131072;          // 256
static constexpr size_t o_yn  = o_D   + 256;             // 2048
static constexpr size_t o_AY  = o_yn  + 2048;            // float2[B*M] -> 1048576 floats
static constexpr size_t o_AYt = o_AY  + 1048576;         // [2][256][2048] = 1048576
static constexpr size_t o_w2t = o_AYt + 1048576;         // Wa f16 [oc=64][kk=9][ic=32] = 18432 halfs
static constexpr size_t o_z1  = o_w2t + 18432;           // z1t f16 [258][2050][32] = 16.92M halfs
static constexpr size_t o_fp  = o_z1  + 16777216;        // [8][64][2048] fp32 partials
static constexpr size_t o_f   = o_fp  + 2097152;         // [64][2048]
static constexpr size_t o_c   = o_f   + 131072;          // [2048][9]
static constexpr size_t o_dd  = o_c   + 18432;           // [2048][9]
static constexpr size_t o_T   = o_dd  + 18432;           // [2048][10]
static constexpr size_t o_Ua  = o_T   + 20480;           // 524288
static constexpr size_t o_gm  = o_Ua  + 524288;          // 1 (uint bits of max)

#define Z1T_RS (2050 * 32)   // z1t row stride in halfs

__device__ __forceinline__ void split2(float x, _Float16& h, _Float16& l) {
    h = (_Float16)x;
    l = (_Float16)(x - (float)h);
}

// ---------------- K0: AA = A^H A, stored as f16 hi/lo planes; D = diag ----------------
__global__ void k_aa(const float* __restrict__ Ar, const float* __restrict__ Ai,
                     float* __restrict__ ws) {
    __shared__ float cr[NM], ci[NM];
    int i = blockIdx.x, j = threadIdx.x;
    if (j < NM) { cr[j] = Ar[j * M_N + i]; ci[j] = Ai[j * M_N + i]; }
    __syncthreads();
    float sr = 0.f, si = 0.f;
    for (int n = 0; n < NM; ++n) {
        float ar = Ar[n * M_N + j], ai = Ai[n * M_N + j];
        sr += cr[n] * ar + ci[n] * ai;
        si += cr[n] * ai - ci[n] * ar;
    }
    _Float16* A16 = (_Float16*)(ws + o_AA);
    size_t off = (size_t)i * M_N + j;
    _Float16 h, l;
    split2(sr, h, l); A16[off] = h;          A16[65536 + off]  = l;
    split2(si, h, l); A16[131072 + off] = h; A16[196608 + off] = l;
    if (j == i) ws[o_D + i] = sr;
}

// ---------------- K0b: Wa[oc][kk][ic] f16 from w2[oc][ic][3][3] ----------------
__global__ void k_w2t(const float* __restrict__ w2, float* __restrict__ ws) {
    int i = blockIdx.x * 256 + threadIdx.x;
    if (i < 64 * 32 * 9) {
        int oc = i / 288, r = i % 288;
        int ic = r / 9, kk = r % 9;
        _Float16* Wa = (_Float16*)(ws + o_w2t);
        Wa[((size_t)oc * 9 + kk) * 32 + ic] = (_Float16)w2[i];
    }
}

// ---------------- K1: AY = A^H Y, ||Y||^2, transposed layout for conv ----------------
__global__ void k_ay(const float* __restrict__ Yr, const float* __restrict__ Yi,
                     const float* __restrict__ Ar, const float* __restrict__ Ai,
                     float* __restrict__ ws) {
    __shared__ float2 Ys[8][NM];
    int bb0 = blockIdx.x * 8;
    int tid = threadIdx.x;
    for (int i = tid; i < 8 * NM; i += 256) {
        int g = i >> 7, n = i & 127;
        Ys[g][n] = make_float2(Yr[(size_t)(bb0 + g) * NM + n], Yi[(size_t)(bb0 + g) * NM + n]);
    }
    __syncthreads();
    if (tid < 8) {
        float s = 0.f;
        for (int n = 0; n < NM; ++n) { float2 y = Ys[tid][n]; s += y.x * y.x + y.y * y.y; }
        ws[o_yn + bb0 + tid] = s;
    }
    int m = tid;
    float accr[8], acci[8];
#pragma unroll
    for (int g = 0; g < 8; ++g) { accr[g] = 0.f; acci[g] = 0.f; }
    for (int n = 0; n < NM; ++n) {
        float ar = Ar[n * M_N + m], ai = Ai[n * M_N + m];
#pragma unroll
        for (int g = 0; g < 8; ++g) {
            float2 y = Ys[g][n];
            accr[g] += ar * y.x + ai * y.y;
            acci[g] += ar * y.y - ai * y.x;
        }
    }
    float2* AY = (float2*)(ws + o_AY);
#pragma unroll
    for (int g = 0; g < 8; ++g) {
        AY[(size_t)(bb0 + g) * M_N + m] = make_float2(accr[g], acci[g]);
        ws[o_AYt + (size_t)m * B_N + (bb0 + g)] = accr[g];
        ws[o_AYt + 524288 + (size_t)m * B_N + (bb0 + g)] = acci[g];
    }
}

// ---------------- K2: conv1 (2->32) + ReLU -> z1t f16 [m+1][b+1][ic], zero halo ----------
__global__ void k_conv1(const float* __restrict__ w1, const float* __restrict__ b1,
                        float* __restrict__ ws) {
    __shared__ float w1s[576], b1s[32];
    int tid = threadIdx.x;
    for (int i = tid; i < 576; i += 256) w1s[i] = w1[i];
    if (tid < 32) b1s[tid] = b1[tid];
    __syncthreads();
    int gidx = blockIdx.x * 256 + tid;
    int b = gidx & (B_N - 1), m = gidx >> 11;
    const float* xr = ws + o_AYt;
    float x[2][3][3];
#pragma unroll
    for (int c = 0; c < 2; ++c)
#pragma unroll
        for (int dm = 0; dm < 3; ++dm) {
            int mm = m + dm - 1;
#pragma unroll
            for (int db = 0; db < 3; ++db) {
                int bb = b + db - 1;
                x[c][dm][db] = (mm >= 0 && mm < M_N && bb >= 0 && bb < B_N)
                                 ? xr[(size_t)c * 524288 + (size_t)mm * B_N + bb] : 0.f;
            }
        }
    _Float16* z1t = (_Float16*)(ws + o_z1);
    _Float16 zv[32];
    for (int oc = 0; oc < 32; ++oc) {
        float acc = b1s[oc];
#pragma unroll
        for (int c = 0; c < 2; ++c)
#pragma unroll
            for (int dm = 0; dm < 3; ++dm)
#pragma unroll
                for (int db = 0; db < 3; ++db)
                    acc += x[c][dm][db] * w1s[oc * 18 + c * 9 + dm * 3 + db];
        zv[oc] = (_Float16)fmaxf(acc, 0.f);
    }
    _Float16* dst = z1t + (size_t)(m + 1) * Z1T_RS + (size_t)(b + 1) * 32;
#pragma unroll
    for (int v = 0; v < 4; ++v) *(half8*)(dst + v * 8) = *(half8*)(zv + v * 8);
    // zero halo
    half8 z8 = (half8)((_Float16)0.f);
    if (m == 0) {
        _Float16* d2 = z1t + (size_t)(b + 1) * 32;
#pragma unroll
        for (int v = 0; v < 4; ++v) *(half8*)(d2 + v * 8) = z8;
        if (b == 0) { _Float16* d3 = z1t;
#pragma unroll
            for (int v = 0; v < 4; ++v) *(half8*)(d3 + v * 8) = z8; }
        if (b == B_N - 1) { _Float16* d3 = z1t + (size_t)2049 * 32;
#pragma unroll
            for (int v = 0; v < 4; ++v) *(half8*)(d3 + v * 8) = z8; }
    }
    if (m == M_N - 1) {
        _Float16* d2 = z1t + (size_t)257 * Z1T_RS + (size_t)(b + 1) * 32;
#pragma unroll
        for (int v = 0; v < 4; ++v) *(half8*)(d2 + v * 8) = z8;
        if (b == 0) { _Float16* d3 = z1t + (size_t)257 * Z1T_RS;
#pragma unroll
            for (int v = 0; v < 4; ++v) *(half8*)(d3 + v * 8) = z8; }
        if (b == B_N - 1) { _Float16* d3 = z1t + (size_t)257 * Z1T_RS + (size_t)2049 * 32;
#pragma unroll
            for (int v = 0; v < 4; ++v) *(half8*)(d3 + v * 8) = z8; }
    }
    if (b == 0) {
        _Float16* d2 = z1t + (size_t)(m + 1) * Z1T_RS;
#pragma unroll
        for (int v = 0; v < 4; ++v) *(half8*)(d2 + v * 8) = z8;
    }
    if (b == B_N - 1) {
        _Float16* d2 = z1t + (size_t)(m + 1) * Z1T_RS + (size_t)2049 * 32;
#pragma unroll
        for (int v = 0; v < 4; ++v) *(half8*)(d2 + v * 8) = z8;
    }
}

// ---------------- K3: conv2 as implicit-GEMM MFMA + ReLU + mean-partial ----------------
// grid 1024 = 128 b-tiles(16) x 8 m-groups(32 rows). block 128 = 2 waves (32 oc each).
// K ordered kk-outer/ic-inner: per tap one K=32 MFMA. B-frags from z1t global
// (16B/lane contiguous), 3-row ring reuses taps across the m sweep. No LDS, no barriers.
#define MFMA16(A,Bv,C) C = __builtin_amdgcn_mfma_f32_16x16x32_f16(A, Bv, C, 0, 0, 0)
__global__ void __launch_bounds__(128)
k_conv2m(const float* __restrict__ b2, float* __restrict__ ws) {
    int tid = threadIdx.x;
    int lane = tid & 63, wv = tid >> 6;
    int col = lane & 15, quad = lane >> 4;
    int bt = blockIdx.x & 127, g = blockIdx.x >> 7;
    int b0 = bt * 16, m0 = g * 32;
    int oc0w = wv * 32;
    const _Float16* z1t = (const _Float16*)(ws + o_z1);
    const _Float16* Wa  = (const _Float16*)(ws + o_w2t);

    // A-fragments: [octile][kk], oc = oc0w + t*16 + col
    half8 Af[2][9];
#pragma unroll
    for (int t = 0; t < 2; ++t)
#pragma unroll
        for (int kk = 0; kk < 9; ++kk)
            Af[t][kk] = *(const half8*)(Wa + ((size_t)(oc0w + t * 16 + col) * 9 + kk) * 32 + quad * 8);
    float bias[2][4];
#pragma unroll
    for (int t = 0; t < 2; ++t)
#pragma unroll
        for (int r = 0; r < 4; ++r)
            bias[t][r] = b2[oc0w + t * 16 + quad * 4 + r];

    // B ring: Bf[phase][db] holds z row m0+... ; lane reads z1t[row][b0+db+col][quad*8..]
    const _Float16* zb = z1t + (size_t)(b0 + col) * 32 + quad * 8;
    half8 Bf[3][3];
#pragma unroll
    for (int ph = 0; ph < 3; ++ph)
#pragma unroll
        for (int db = 0; db < 3; ++db)
            Bf[ph][db] = *(const half8*)(zb + (size_t)(m0 + ph) * Z1T_RS + (size_t)db * 32);

    floatx4 facc[2];
    facc[0] = (floatx4){0.f, 0.f, 0.f, 0.f};
    facc[1] = (floatx4){0.f, 0.f, 0.f, 0.f};

#pragma unroll
    for (int mm = 0; mm < 32; ++mm) {
        floatx4 a0 = (floatx4){0.f, 0.f, 0.f, 0.f};
        floatx4 a1 = (floatx4){0.f, 0.f, 0.f, 0.f};
#pragma unroll
        for (int dm = 0; dm < 3; ++dm) {
            int ph = (mm + dm) % 3;
#pragma unroll
            for (int db = 0; db < 3; ++db) {
                MFMA16(Af[0][dm * 3 + db], Bf[ph][db], a0);
                MFMA16(Af[1][dm * 3 + db], Bf[ph][db], a1);
            }
        }
#pragma unroll
        for (int r = 0; r < 4; ++r) {
            facc[0][r] += fmaxf(a0[r] + bias[0][r], 0.f);
            facc[1][r] += fmaxf(a1[r] + bias[1][r], 0.f);
        }
        if (mm < 31) {
            int ph = mm % 3;                    // oldest row, no longer needed
#pragma unroll
            for (int db = 0; db < 3; ++db)
                Bf[ph][db] = *(const half8*)(zb + (size_t)(m0 + mm + 3) * Z1T_RS + (size_t)db * 32);
        }
    }
    float* fp = ws + o_fp + (size_t)g * 131072;
#pragma unroll
    for (int t = 0; t < 2; ++t)
#pragma unroll
        for (int r = 0; r < 4; ++r)
            fp[(size_t)(oc0w + t * 16 + quad * 4 + r) * B_N + b0 + col] = facc[t][r];
}

// ---------------- K3b: reduce 8 partials -> f = mean over M ----------------
__global__ void k_fred(float* __restrict__ ws) {
    size_t i = (size_t)blockIdx.x * 256 + threadIdx.x;
    float s = 0.f;
    for (int p = 0; p < 8; ++p) s += ws[o_fp + (size_t)p * 131072 + i];
    ws[o_f + i] = s * (1.f / 256.f);
}

// ---------------- K4: c,d,T 1-D convs over batch axis ----------------
__global__ void k_cdt(const float* __restrict__ hcw, const float* __restrict__ hcb,
                      const float* __restrict__ hdw, const float* __restrict__ hdb,
                      const float* __restrict__ hTw, const float* __restrict__ hTb,
                      float* __restrict__ ws, float* __restrict__ out) {
    int b = (blockIdx.x & 7) * 256 + threadIdx.x;
    int grp = blockIdx.x >> 3;
    const float* f = ws + o_f;
    const float* w; const float* bi; int cnt, l0;
    if (grp == 0)      { w = hcw; bi = hcb; cnt = 9; l0 = 0; }
    else if (grp == 1) { w = hdw; bi = hdb; cnt = 9; l0 = 0; }
    else if (grp == 2) { w = hTw; bi = hTb; cnt = 5; l0 = 0; }
    else               { w = hTw; bi = hTb; cnt = 5; l0 = 5; }
    float acc[9];
    for (int i = 0; i < cnt; ++i) acc[i] = bi[l0 + i];
    bool okL = (b > 0), okR = (b < B_N - 1);
    for (int ic = 0; ic < 64; ++ic) {
        const float* fr = f + (size_t)ic * B_N + b;
        float fm1 = okL ? fr[-1] : 0.f;
        float f0  = fr[0];
        float fp1 = okR ? fr[1] : 0.f;
        for (int i = 0; i < cnt; ++i) {
            const float* wr = w + (size_t)(l0 + i) * 192 + ic * 3;
            acc[i] += fm1 * wr[0] + f0 * wr[1] + fp1 * wr[2];
        }
    }
    for (int i = 0; i < cnt; ++i) {
        float v = fmaxf(fabsf(acc[i]), 1e-6f);
        if (grp != 1) v = fminf(v, 100.f);
        int l = l0 + i;
        if (grp == 0)      { ws[o_c  + (size_t)b * 9  + l] = v; if (b == B_N - 1) out[524288 + l] = v; }
        else if (grp == 1) { ws[o_dd + (size_t)b * 9  + l] = v; if (b == B_N - 1) out[524297 + l] = v; }
        else               { ws[o_T  + (size_t)b * 10 + l] = v; if (b == B_N - 1) out[524306 + l] = v; }
    }
}

// ---------------- K5: 10-layer iteration via f16x3 MFMA ----------------
__global__ void __launch_bounds__(512, 2)
k_iter(const float* __restrict__ a0p, const float* __restrict__ b0p, float* __restrict__ ws) {
    __shared__ __align__(16) _Float16 Ub[6][16][264];
    __shared__ float redv[8][16][3];
    __shared__ float redm[8];
    int tid = threadIdx.x;
    int lane = tid & 63, w = tid >> 6;
    int col = lane & 15, quad = lane >> 4;
    int bb0 = blockIdx.x * 16;
    int b = bb0 + col;
    const float2* AY = (const float2*)(ws + o_AY);
    const _Float16* Arh = (const _Float16*)(ws + o_AA);
    const _Float16* Arl = Arh + 65536;
    const _Float16* Aih = Arh + 131072;
    const _Float16* Ail = Arh + 196608;
    float a0 = a0p[0], b0v = b0p[0];
    float atot = a0 + (float)NM;
    float yn = ws[o_yn + b];
    float eps = a0 / b0v;
    float lam0 = ws[o_c + (size_t)b * 9] / ws[o_dd + (size_t)b * 9];
    float Dv[2][4], ayr[2][4], ayi[2][4], lam[2][4], Ur[2][4], Ui[2][4], sg[2][4];
    floatx4 wr[2], wi[2];
#pragma unroll
    for (int t = 0; t < 2; ++t) {
        wr[t] = (floatx4){0.f, 0.f, 0.f, 0.f};
        wi[t] = (floatx4){0.f, 0.f, 0.f, 0.f};
#pragma unroll
        for (int r = 0; r < 4; ++r) {
            int m = w * 32 + t * 16 + quad * 4 + r;
            Dv[t][r] = ws[o_D + m];
            float2 a = AY[(size_t)b * M_N + m];
            ayr[t][r] = a.x; ayi[t][r] = a.y;
            lam[t][r] = lam0;
            Ur[t][r] = 0.f; Ui[t][r] = 0.f;
        }
    }
    for (int k = 0; k < LNUM; ++k) {
        float Tk = ws[o_T + (size_t)b * 10 + k];
#pragma unroll
        for (int t = 0; t < 2; ++t)
#pragma unroll
            for (int r = 0; r < 4; ++r) {
                float iv = eps / (eps * Tk + lam[t][r] + EPS_Sf);
                Ur[t][r] = iv * (Tk * Ur[t][r] - wr[t][r] + ayr[t][r]);
                Ui[t][r] = iv * (Tk * Ui[t][r] - wi[t][r] + ayi[t][r]);
            }
        if (k == LNUM - 1) break;
#pragma unroll
        for (int t = 0; t < 2; ++t) {
            int j0 = w * 32 + t * 16 + quad * 4;
            _Float16 rh[4], rl[4], ih[4], il[4];
#pragma unroll
            for (int r = 0; r < 4; ++r) {
                split2(Ur[t][r], rh[r], rl[r]);
                split2(Ui[t][r], ih[r], il[r]);
            }
            _Float16* bp = &Ub[0][col][j0];
#pragma unroll
            for (int c2 = 0; c2 < 6; ++c2) {
                _Float16 h0, h1, h2, h3;
                if (c2 == 0)      { h0 = rh[0]; h1 = rh[1]; h2 = rh[2]; h3 = rh[3]; }
                else if (c2 == 1) { h0 = rl[0]; h1 = rl[1]; h2 = rl[2]; h3 = rl[3]; }
                else if (c2 == 2) { h0 = ih[0]; h1 = ih[1]; h2 = ih[2]; h3 = ih[3]; }
                else if (c2 == 3) { h0 = il[0]; h1 = il[1]; h2 = il[2]; h3 = il[3]; }
                else if (c2 == 4) { h0 = -ih[0]; h1 = -ih[1]; h2 = -ih[2]; h3 = -ih[3]; }
                else              { h0 = -il[0]; h1 = -il[1]; h2 = -il[2]; h3 = -il[3]; }
                union { _Float16 h[2]; unsigned u; } p0, p1;
                p0.h[0] = h0; p0.h[1] = h1; p1.h[0] = h2; p1.h[1] = h3;
                *(unsigned*)(bp + (size_t)c2 * 4224)     = p0.u;
                *(unsigned*)(bp + (size_t)c2 * 4224 + 2) = p1.u;
            }
        }
        __syncthreads();
        wr[0] = (floatx4){0.f, 0.f, 0.f, 0.f}; wi[0] = (floatx4){0.f, 0.f, 0.f, 0.f};
        wr[1] = (floatx4){0.f, 0.f, 0.f, 0.f}; wi[1] = (floatx4){0.f, 0.f, 0.f, 0.f};
        for (int ks = 0; ks < 8; ++ks) {
            int j0 = ks * 32 + quad * 8;
            const _Float16* ub = &Ub[0][col][j0];
            half8 urh = *(const half8*)(ub);
            half8 url = *(const half8*)(ub + 4224);
            half8 uih = *(const half8*)(ub + 2 * 4224);
            half8 uil = *(const half8*)(ub + 3 * 4224);
            half8 nih = *(const half8*)(ub + 4 * 4224);
            half8 nil_ = *(const half8*)(ub + 5 * 4224);
#pragma unroll
            for (int t = 0; t < 2; ++t) {
                size_t ao = (size_t)(w * 32 + t * 16 + col) * M_N + j0;
                half8 arh = *(const half8*)(Arh + ao);
                half8 arl = *(const half8*)(Arl + ao);
                half8 aih = *(const half8*)(Aih + ao);
                half8 ail = *(const half8*)(Ail + ao);
                MFMA16(arh, urh, wr[t]);
                MFMA16(arh, url, wr[t]);
                MFMA16(arl, urh, wr[t]);
                MFMA16(aih, nih, wr[t]);
                MFMA16(aih, nil_, wr[t]);
                MFMA16(ail, nih, wr[t]);
                MFMA16(arh, uih, wi[t]);
                MFMA16(arh, uil, wi[t]);
                MFMA16(arl, uih, wi[t]);
                MFMA16(aih, urh, wi[t]);
                MFMA16(aih, url, wi[t]);
                MFMA16(ail, urh, wi[t]);
            }
        }
        float p1 = 0.f, p2 = 0.f, p3 = 0.f;
#pragma unroll
        for (int t = 0; t < 2; ++t)
#pragma unroll
            for (int r = 0; r < 4; ++r) {
                sg[t][r] = 1.f / (eps * Dv[t][r] + lam[t][r] + EPS_Sf);
                p1 += ayr[t][r] * Ur[t][r] + ayi[t][r] * Ui[t][r];
                p2 += Ur[t][r] * wr[t][r] + Ui[t][r] * wi[t][r];
                p3 += Dv[t][r] * sg[t][r];
            }
        p1 += __shfl_xor(p1, 16); p1 += __shfl_xor(p1, 32);
        p2 += __shfl_xor(p2, 16); p2 += __shfl_xor(p2, 32);
        p3 += __shfl_xor(p3, 16); p3 += __shfl_xor(p3, 32);
        if (lane < 16) { redv[w][col][0] = p1; redv[w][col][1] = p2; redv[w][col][2] = p3; }
        __syncthreads();
        float s1 = 0.f, s2 = 0.f, s3 = 0.f;
#pragma unroll
        for (int u8 = 0; u8 < 8; ++u8) {
            s1 += redv[u8][col][0]; s2 += redv[u8][col][1]; s3 += redv[u8][col][2];
        }
        float eps1 = fmaxf(yn - 2.f * s1 + s2, 0.f);
        eps = atot / (b0v + eps1 + s3 + EPS_Sf);
        float ck = ws[o_c + (size_t)b * 9 + k];
        float dk = ws[o_dd + (size_t)b * 9 + k];
#pragma unroll
        for (int t = 0; t < 2; ++t)
#pragma unroll
            for (int r = 0; r < 4; ++r)
                lam[t][r] = (ck + 1.f) / (dk + Ur[t][r] * Ur[t][r] + Ui[t][r] * Ui[t][r]
                                          + sg[t][r] + EPS_Sf);
    }
    float lm = 0.f;
#pragma unroll
    for (int t = 0; t < 2; ++t) {
        float4 v;
        v.x = sqrtf(Ur[t][0] * Ur[t][0] + Ui[t][0] * Ui[t][0]);
        v.y = sqrtf(Ur[t][1] * Ur[t][1] + Ui[t][1] * Ui[t][1]);
        v.z = sqrtf(Ur[t][2] * Ur[t][2] + Ui[t][2] * Ui[t][2]);
        v.w = sqrtf(Ur[t][3] * Ur[t][3] + Ui[t][3] * Ui[t][3]);
        lm = fmaxf(lm, fmaxf(fmaxf(v.x, v.y), fmaxf(v.z, v.w)));
        *(float4*)&ws[o_Ua + (size_t)b * M_N + w * 32 + t * 16 + quad * 4] = v;
    }
#pragma unroll
    for (int off = 32; off >= 1; off >>= 1) lm = fmaxf(lm, __shfl_xor(lm, off));
    if (lane == 0) redm[w] = lm;
    __syncthreads();
    if (tid == 0) {
        float mx = redm[0];
#pragma unroll
        for (int i = 1; i < 8; ++i) mx = fmaxf(mx, redm[i]);
        atomicMax((unsigned int*)(ws + o_gm), __float_as_uint(mx));
    }
}

// ---------------- K6: normalize ----------------
__global__ void k_norm(const float* __restrict__ ws, float* __restrict__ out) {
    size_t i = (size_t)blockIdx.x * 256 + threadIdx.x;
    float gm = __uint_as_float(*(const unsigned int*)(ws + o_gm));
    out[i] = ws[o_Ua + i] / (gm + 1e-8f);
}

extern "C" void kernel_launch(void* const* d_in, const int* in_sizes, int n_in,
                              void* d_out, int out_size, void* d_ws, size_t ws_size,
                              hipStream_t stream) {
    (void)in_sizes; (void)n_in; (void)out_size; (void)ws_size;
    const float* Yr  = (const float*)d_in[0];
    const float* Yi  = (const float*)d_in[1];
    const float* Ar  = (const float*)d_in[2];
    const float* Ai  = (const float*)d_in[3];
    const float* w1  = (const float*)d_in[4];
    const float* b1  = (const float*)d_in[5];
    const float* w2  = (const float*)d_in[6];
    const float* b2  = (const float*)d_in[7];
    const float* hcw = (const float*)d_in[8];
    const float* hcb = (const float*)d_in[9];
    const float* hdw = (const float*)d_in[10];
    const float* hdb = (const float*)d_in[11];
    const float* hTw = (const float*)d_in[12];
    const float* hTb = (const float*)d_in[13];
    const float* a0  = (const float*)d_in[14];
    const float* b0  = (const float*)d_in[15];
    float* ws = (float*)d_ws;
    float* out = (float*)d_out;

    hipMemsetAsync((char*)d_ws + o_gm * sizeof(float), 0, 4, stream);
    k_aa    <<<256, 256, 0, stream>>>(Ar, Ai, ws);
    k_w2t   <<<72, 256, 0, stream>>>(w2, ws);
    k_ay    <<<256, 256, 0, stream>>>(Yr, Yi, Ar, Ai, ws);
    k_conv1 <<<2048, 256, 0, stream>>>(w1, b1, ws);
    k_conv2m<<<1024, 128, 0, stream>>>(b2, ws);
    k_fred  <<<512, 256, 0, stream>>>(ws);
    k_cdt   <<<32, 256, 0, stream>>>(hcw, hcb, hdw, hdb, hTw, hTb, ws, out);
    k_iter  <<<128, 512, 0, stream>>>(a0, b0, ws);
    k_norm  <<<2048, 256, 0, stream>>>(ws, out);
}

// Round 5
// 335.279 us; speedup vs baseline: 5.0661x; 1.1947x over previous
//
#include <hip/hip_runtime.h>
#include <math.h>

#define B_N   2048
#define NM    128
#define M_N   256
#define LNUM  10
#define EPS_Sf 1e-6f

typedef _Float16 half8 __attribute__((ext_vector_type(8)));
typedef float floatx4 __attribute__((ext_vector_type(4)));

// ---------------- workspace layout (float offsets) ----------------
// o_AA: 4 f16 planes of AA in MFMA-A-fragment order [plane][tile16][ks8][lane64][e8]
//       planes: AAr_hi | AAr_lo | AAi_hi | AAi_lo (65536 halfs each)
static constexpr size_t o_AA  = 0;                       // 131072 floats
static constexpr size_t o_D   = o_AA  + 131072;          // 256
static constexpr size_t o_yn  = o_D   + 256;             // 2048
static constexpr size_t o_AY  = o_yn  + 2048;            // float2[B*M] -> 1048576 floats
static constexpr size_t o_AYt = o_AY  + 1048576;         // [2][256][2048] = 1048576
static constexpr size_t o_w2t = o_AYt + 1048576;         // Wa f16 [oc=64][kk=9][ic=32]
static constexpr size_t o_z1  = o_w2t + 18432;           // z1t f16 [258][2050][32]
static constexpr size_t o_fp  = o_z1  + 16777216;        // [8][64][2048] fp32 partials
static constexpr size_t o_f   = o_fp  + 2097152;         // [64][2048]
static constexpr size_t o_c   = o_f   + 131072;          // [2048][9]
static constexpr size_t o_dd  = o_c   + 18432;           // [2048][9]
static constexpr size_t o_T   = o_dd  + 18432;           // [2048][10]
static constexpr size_t o_Ua  = o_T   + 20480;           // 524288
static constexpr size_t o_gm  = o_Ua  + 524288;          // 1 (uint bits of max)

#define Z1T_RS (2050 * 32)   // z1t row stride in halfs

__device__ __forceinline__ void split2(float x, _Float16& h, _Float16& l) {
    h = (_Float16)x;
    l = (_Float16)(x - (float)h);
}

// ---------------- K0: AA = A^H A -> f16 hi/lo planes in fragment order; D = diag ------
__global__ void k_aa(const float* __restrict__ Ar, const float* __restrict__ Ai,
                     float* __restrict__ ws) {
    __shared__ float cr[NM], ci[NM];
    int i = blockIdx.x, j = threadIdx.x;      // i = m row, j = K col
    if (j < NM) { cr[j] = Ar[j * M_N + i]; ci[j] = Ai[j * M_N + i]; }
    __syncthreads();
    float sr = 0.f, si = 0.f;
    for (int n = 0; n < NM; ++n) {
        float ar = Ar[n * M_N + j], ai = Ai[n * M_N + j];
        sr += cr[n] * ar + ci[n] * ai;
        si += cr[n] * ai - ci[n] * ar;
    }
    _Float16* A16 = (_Float16*)(ws + o_AA);
    // fragment order: ((tile*8 + ks)*64 + lane)*8 + e ; lane = quad*16 + (i&15)
    size_t off = ((size_t)((i >> 4) * 8 + (j >> 5)) * 64
                  + (size_t)(((j >> 3) & 3) * 16 + (i & 15))) * 8 + (j & 7);
    _Float16 h, l;
    split2(sr, h, l); A16[off] = h;          A16[65536 + off]  = l;
    split2(si, h, l); A16[131072 + off] = h; A16[196608 + off] = l;
    if (j == i) ws[o_D + i] = sr;
}

// ---------------- K0b: Wa[oc][kk][ic] f16 from w2[oc][ic][3][3] ----------------
__global__ void k_w2t(const float* __restrict__ w2, float* __restrict__ ws) {
    int i = blockIdx.x * 256 + threadIdx.x;
    if (i < 64 * 32 * 9) {
        int oc = i / 288, r = i % 288;
        int ic = r / 9, kk = r % 9;
        _Float16* Wa = (_Float16*)(ws + o_w2t);
        Wa[((size_t)oc * 9 + kk) * 32 + ic] = (_Float16)w2[i];
    }
}

// ---------------- K1: AY = A^H Y, ||Y||^2, transposed layout for conv ----------------
__global__ void k_ay(const float* __restrict__ Yr, const float* __restrict__ Yi,
                     const float* __restrict__ Ar, const float* __restrict__ Ai,
                     float* __restrict__ ws) {
    __shared__ float2 Ys[8][NM];
    int bb0 = blockIdx.x * 8;
    int tid = threadIdx.x;
    for (int i = tid; i < 8 * NM; i += 256) {
        int g = i >> 7, n = i & 127;
        Ys[g][n] = make_float2(Yr[(size_t)(bb0 + g) * NM + n], Yi[(size_t)(bb0 + g) * NM + n]);
    }
    __syncthreads();
    if (tid < 8) {
        float s = 0.f;
        for (int n = 0; n < NM; ++n) { float2 y = Ys[tid][n]; s += y.x * y.x + y.y * y.y; }
        ws[o_yn + bb0 + tid] = s;
    }
    int m = tid;
    float accr[8], acci[8];
#pragma unroll
    for (int g = 0; g < 8; ++g) { accr[g] = 0.f; acci[g] = 0.f; }
    for (int n = 0; n < NM; ++n) {
        float ar = Ar[n * M_N + m], ai = Ai[n * M_N + m];
#pragma unroll
        for (int g = 0; g < 8; ++g) {
            float2 y = Ys[g][n];
            accr[g] += ar * y.x + ai * y.y;
            acci[g] += ar * y.y - ai * y.x;
        }
    }
    float2* AY = (float2*)(ws + o_AY);
#pragma unroll
    for (int g = 0; g < 8; ++g) {
        AY[(size_t)(bb0 + g) * M_N + m] = make_float2(accr[g], acci[g]);
        ws[o_AYt + (size_t)m * B_N + (bb0 + g)] = accr[g];
        ws[o_AYt + 524288 + (size_t)m * B_N + (bb0 + g)] = acci[g];
    }
}

// ---------------- K2: conv1 (2->32) + ReLU -> z1t f16 [m+1][b+1][ic], zero halo ----------
__global__ void k_conv1(const float* __restrict__ w1, const float* __restrict__ b1,
                        float* __restrict__ ws) {
    __shared__ float w1s[576], b1s[32];
    int tid = threadIdx.x;
    for (int i = tid; i < 576; i += 256) w1s[i] = w1[i];
    if (tid < 32) b1s[tid] = b1[tid];
    __syncthreads();
    int gidx = blockIdx.x * 256 + tid;
    int b = gidx & (B_N - 1), m = gidx >> 11;
    const float* xr = ws + o_AYt;
    float x[2][3][3];
#pragma unroll
    for (int c = 0; c < 2; ++c)
#pragma unroll
        for (int dm = 0; dm < 3; ++dm) {
            int mm = m + dm - 1;
#pragma unroll
            for (int db = 0; db < 3; ++db) {
                int bb = b + db - 1;
                x[c][dm][db] = (mm >= 0 && mm < M_N && bb >= 0 && bb < B_N)
                                 ? xr[(size_t)c * 524288 + (size_t)mm * B_N + bb] : 0.f;
            }
        }
    _Float16* z1t = (_Float16*)(ws + o_z1);
    _Float16 zv[32];
    for (int oc = 0; oc < 32; ++oc) {
        float acc = b1s[oc];
#pragma unroll
        for (int c = 0; c < 2; ++c)
#pragma unroll
            for (int dm = 0; dm < 3; ++dm)
#pragma unroll
                for (int db = 0; db < 3; ++db)
                    acc += x[c][dm][db] * w1s[oc * 18 + c * 9 + dm * 3 + db];
        zv[oc] = (_Float16)fmaxf(acc, 0.f);
    }
    _Float16* dst = z1t + (size_t)(m + 1) * Z1T_RS + (size_t)(b + 1) * 32;
#pragma unroll
    for (int v = 0; v < 4; ++v) *(half8*)(dst + v * 8) = *(half8*)(zv + v * 8);
    half8 z8 = (half8)((_Float16)0.f);
    if (m == 0) {
        _Float16* d2 = z1t + (size_t)(b + 1) * 32;
#pragma unroll
        for (int v = 0; v < 4; ++v) *(half8*)(d2 + v * 8) = z8;
        if (b == 0) { _Float16* d3 = z1t;
#pragma unroll
            for (int v = 0; v < 4; ++v) *(half8*)(d3 + v * 8) = z8; }
        if (b == B_N - 1) { _Float16* d3 = z1t + (size_t)2049 * 32;
#pragma unroll
            for (int v = 0; v < 4; ++v) *(half8*)(d3 + v * 8) = z8; }
    }
    if (m == M_N - 1) {
        _Float16* d2 = z1t + (size_t)257 * Z1T_RS + (size_t)(b + 1) * 32;
#pragma unroll
        for (int v = 0; v < 4; ++v) *(half8*)(d2 + v * 8) = z8;
        if (b == 0) { _Float16* d3 = z1t + (size_t)257 * Z1T_RS;
#pragma unroll
            for (int v = 0; v < 4; ++v) *(half8*)(d3 + v * 8) = z8; }
        if (b == B_N - 1) { _Float16* d3 = z1t + (size_t)257 * Z1T_RS + (size_t)2049 * 32;
#pragma unroll
            for (int v = 0; v < 4; ++v) *(half8*)(d3 + v * 8) = z8; }
    }
    if (b == 0) {
        _Float16* d2 = z1t + (size_t)(m + 1) * Z1T_RS;
#pragma unroll
        for (int v = 0; v < 4; ++v) *(half8*)(d2 + v * 8) = z8;
    }
    if (b == B_N - 1) {
        _Float16* d2 = z1t + (size_t)(m + 1) * Z1T_RS + (size_t)2049 * 32;
#pragma unroll
        for (int v = 0; v < 4; ++v) *(half8*)(d2 + v * 8) = z8;
    }
}

// ---------------- K3: conv2 as implicit-GEMM MFMA + ReLU + mean-partial ----------------
#define MFMA16(A,Bv,C) C = __builtin_amdgcn_mfma_f32_16x16x32_f16(A, Bv, C, 0, 0, 0)
__global__ void __launch_bounds__(128)
k_conv2m(const float* __restrict__ b2, float* __restrict__ ws) {
    int tid = threadIdx.x;
    int lane = tid & 63, wv = tid >> 6;
    int col = lane & 15, quad = lane >> 4;
    int bt = blockIdx.x & 127, g = blockIdx.x >> 7;
    int b0 = bt * 16, m0 = g * 32;
    int oc0w = wv * 32;
    const _Float16* z1t = (const _Float16*)(ws + o_z1);
    const _Float16* Wa  = (const _Float16*)(ws + o_w2t);

    half8 Af[2][9];
#pragma unroll
    for (int t = 0; t < 2; ++t)
#pragma unroll
        for (int kk = 0; kk < 9; ++kk)
            Af[t][kk] = *(const half8*)(Wa + ((size_t)(oc0w + t * 16 + col) * 9 + kk) * 32 + quad * 8);
    float bias[2][4];
#pragma unroll
    for (int t = 0; t < 2; ++t)
#pragma unroll
        for (int r = 0; r < 4; ++r)
            bias[t][r] = b2[oc0w + t * 16 + quad * 4 + r];

    const _Float16* zb = z1t + (size_t)(b0 + col) * 32 + quad * 8;
    half8 Bf[3][3];
#pragma unroll
    for (int ph = 0; ph < 3; ++ph)
#pragma unroll
        for (int db = 0; db < 3; ++db)
            Bf[ph][db] = *(const half8*)(zb + (size_t)(m0 + ph) * Z1T_RS + (size_t)db * 32);

    floatx4 facc[2];
    facc[0] = (floatx4){0.f, 0.f, 0.f, 0.f};
    facc[1] = (floatx4){0.f, 0.f, 0.f, 0.f};

#pragma unroll
    for (int mm = 0; mm < 32; ++mm) {
        floatx4 a0 = (floatx4){0.f, 0.f, 0.f, 0.f};
        floatx4 a1 = (floatx4){0.f, 0.f, 0.f, 0.f};
#pragma unroll
        for (int dm = 0; dm < 3; ++dm) {
            int ph = (mm + dm) % 3;
#pragma unroll
            for (int db = 0; db < 3; ++db) {
                MFMA16(Af[0][dm * 3 + db], Bf[ph][db], a0);
                MFMA16(Af[1][dm * 3 + db], Bf[ph][db], a1);
            }
        }
#pragma unroll
        for (int r = 0; r < 4; ++r) {
            facc[0][r] += fmaxf(a0[r] + bias[0][r], 0.f);
            facc[1][r] += fmaxf(a1[r] + bias[1][r], 0.f);
        }
        if (mm < 31) {
            int ph = mm % 3;
#pragma unroll
            for (int db = 0; db < 3; ++db)
                Bf[ph][db] = *(const half8*)(zb + (size_t)(m0 + mm + 3) * Z1T_RS + (size_t)db * 32);
        }
    }
    float* fp = ws + o_fp + (size_t)g * 131072;
#pragma unroll
    for (int t = 0; t < 2; ++t)
#pragma unroll
        for (int r = 0; r < 4; ++r)
            fp[(size_t)(oc0w + t * 16 + quad * 4 + r) * B_N + b0 + col] = facc[t][r];
}

// ---------------- K3b: reduce 8 partials -> f = mean over M ----------------
__global__ void k_fred(float* __restrict__ ws) {
    size_t i = (size_t)blockIdx.x * 256 + threadIdx.x;
    float s = 0.f;
    for (int p = 0; p < 8; ++p) s += ws[o_fp + (size_t)p * 131072 + i];
    ws[o_f + i] = s * (1.f / 256.f);
}

// ---------------- K4: c,d,T 1-D convs over batch axis ----------------
__global__ void k_cdt(const float* __restrict__ hcw, const float* __restrict__ hcb,
                      const float* __restrict__ hdw, const float* __restrict__ hdb,
                      const float* __restrict__ hTw, const float* __restrict__ hTb,
                      float* __restrict__ ws, float* __restrict__ out) {
    int b = (blockIdx.x & 7) * 256 + threadIdx.x;
    int grp = blockIdx.x >> 3;
    const float* f = ws + o_f;
    const float* w; const float* bi; int cnt, l0;
    if (grp == 0)      { w = hcw; bi = hcb; cnt = 9; l0 = 0; }
    else if (grp == 1) { w = hdw; bi = hdb; cnt = 9; l0 = 0; }
    else if (grp == 2) { w = hTw; bi = hTb; cnt = 5; l0 = 0; }
    else               { w = hTw; bi = hTb; cnt = 5; l0 = 5; }
    float acc[9];
    for (int i = 0; i < cnt; ++i) acc[i] = bi[l0 + i];
    bool okL = (b > 0), okR = (b < B_N - 1);
    for (int ic = 0; ic < 64; ++ic) {
        const float* fr = f + (size_t)ic * B_N + b;
        float fm1 = okL ? fr[-1] : 0.f;
        float f0  = fr[0];
        float fp1 = okR ? fr[1] : 0.f;
        for (int i = 0; i < cnt; ++i) {
            const float* wr = w + (size_t)(l0 + i) * 192 + ic * 3;
            acc[i] += fm1 * wr[0] + f0 * wr[1] + fp1 * wr[2];
        }
    }
    for (int i = 0; i < cnt; ++i) {
        float v = fmaxf(fabsf(acc[i]), 1e-6f);
        if (grp != 1) v = fminf(v, 100.f);
        int l = l0 + i;
        if (grp == 0)      { ws[o_c  + (size_t)b * 9  + l] = v; if (b == B_N - 1) out[524288 + l] = v; }
        else if (grp == 1) { ws[o_dd + (size_t)b * 9  + l] = v; if (b == B_N - 1) out[524297 + l] = v; }
        else               { ws[o_T  + (size_t)b * 10 + l] = v; if (b == B_N - 1) out[524306 + l] = v; }
    }
}

// ---------------- K5: 10-layer iteration, f16x3 MFMA, 16 waves/block ----------------
// Block: 16 batches (cols) x full m=256; wave w owns rows [w*16, w*16+16).
// A planes pre-swizzled to fragment order (coalesced 1KB wave loads).
// Ub LDS in fragment order [comp4][ks8][lane64][e8]: conflict-free b128 reads.
// wr = (AAr.urh-products) - (AAi.ui-products) via separate accumulators (no neg comps).
__global__ void __launch_bounds__(1024, 4)
k_iter(const float* __restrict__ a0p, const float* __restrict__ b0p, float* __restrict__ ws) {
    __shared__ __align__(16) _Float16 Ubf[4][8][64][8];   // 32 KB
    __shared__ float redv[16][16][3];
    __shared__ float redm[16];
    int tid = threadIdx.x;
    int lane = tid & 63, w = tid >> 6;          // w = 0..15 (row tile)
    int col = lane & 15, quad = lane >> 4;
    int b = blockIdx.x * 16 + col;
    const float2* AY = (const float2*)(ws + o_AY);
    const _Float16* Af = (const _Float16*)(ws + o_AA);
    float a0 = a0p[0], b0v = b0p[0];
    float atot = a0 + (float)NM;
    float yn = ws[o_yn + b];
    float eps = a0 / b0v;
    float lam0 = ws[o_c + (size_t)b * 9] / ws[o_dd + (size_t)b * 9];
    float Dv[4], ayr[4], ayi[4], lam[4], Ur[4], Ui[4], sg[4], wr_[4], wi_[4];
#pragma unroll
    for (int r = 0; r < 4; ++r) {
        int m = w * 16 + quad * 4 + r;
        Dv[r] = ws[o_D + m];
        float2 a = AY[(size_t)b * M_N + m];
        ayr[r] = a.x; ayi[r] = a.y;
        lam[r] = lam0;
        Ur[r] = 0.f; Ui[r] = 0.f; wr_[r] = 0.f; wi_[r] = 0.f;
    }
    // staging destination constants (wave-uniform ks, lane mapping)
    int ksw = w >> 1;
    int quadD = (w & 1) * 2 + (quad >> 1);
    int laneD = quadD * 16 + col;
    int eb = (quad & 1) * 4;
    for (int k = 0; k < LNUM; ++k) {
        float Tk = ws[o_T + (size_t)b * 10 + k];
#pragma unroll
        for (int r = 0; r < 4; ++r) {
            float iv = eps / (eps * Tk + lam[r] + EPS_Sf);
            Ur[r] = iv * (Tk * Ur[r] - wr_[r] + ayr[r]);
            Ui[r] = iv * (Tk * Ui[r] - wi_[r] + ayi[r]);
        }
        if (k == LNUM - 1) break;
        // ---- stage U hi/lo comps to LDS in B-fragment order ----
        {
            union { _Float16 h[4]; unsigned long long u; } c0, c1, c2, c3;
#pragma unroll
            for (int r = 0; r < 4; ++r) {
                _Float16 h, l;
                split2(Ur[r], h, l); c0.h[r] = h; c1.h[r] = l;
                split2(Ui[r], h, l); c2.h[r] = h; c3.h[r] = l;
            }
            *(unsigned long long*)&Ubf[0][ksw][laneD][eb] = c0.u;
            *(unsigned long long*)&Ubf[1][ksw][laneD][eb] = c1.u;
            *(unsigned long long*)&Ubf[2][ksw][laneD][eb] = c2.u;
            *(unsigned long long*)&Ubf[3][ksw][laneD][eb] = c3.u;
        }
        __syncthreads();
        // ---- matvec: w = AA * U ----
        floatx4 wrp = (floatx4){0.f, 0.f, 0.f, 0.f};
        floatx4 wrn = (floatx4){0.f, 0.f, 0.f, 0.f};
        floatx4 wia = (floatx4){0.f, 0.f, 0.f, 0.f};
#pragma unroll
        for (int ks = 0; ks < 8; ++ks) {
            half8 urh = *(const half8*)&Ubf[0][ks][lane][0];
            half8 url = *(const half8*)&Ubf[1][ks][lane][0];
            half8 uih = *(const half8*)&Ubf[2][ks][lane][0];
            half8 uil = *(const half8*)&Ubf[3][ks][lane][0];
            const _Float16* ab = Af + ((size_t)(w * 8 + ks) * 64 + lane) * 8;
            half8 arh = *(const half8*)(ab);
            half8 arl = *(const half8*)(ab + 65536);
            half8 aih = *(const half8*)(ab + 131072);
            half8 ail = *(const half8*)(ab + 196608);
            MFMA16(arh, urh, wrp);
            MFMA16(arh, url, wrp);
            MFMA16(arl, urh, wrp);
            MFMA16(aih, uih, wrn);
            MFMA16(aih, uil, wrn);
            MFMA16(ail, uih, wrn);
            MFMA16(arh, uih, wia);
            MFMA16(arh, uil, wia);
            MFMA16(arl, uih, wia);
            MFMA16(aih, urh, wia);
            MFMA16(aih, url, wia);
            MFMA16(ail, urh, wia);
        }
        // ---- per-batch reductions over m ----
        float p1 = 0.f, p2 = 0.f, p3 = 0.f;
#pragma unroll
        for (int r = 0; r < 4; ++r) {
            wr_[r] = wrp[r] - wrn[r];
            wi_[r] = wia[r];
            sg[r] = 1.f / (eps * Dv[r] + lam[r] + EPS_Sf);
            p1 += ayr[r] * Ur[r] + ayi[r] * Ui[r];
            p2 += Ur[r] * wr_[r] + Ui[r] * wi_[r];
            p3 += Dv[r] * sg[r];
        }
        p1 += __shfl_xor(p1, 16); p1 += __shfl_xor(p1, 32);
        p2 += __shfl_xor(p2, 16); p2 += __shfl_xor(p2, 32);
        p3 += __shfl_xor(p3, 16); p3 += __shfl_xor(p3, 32);
        if (lane < 16) { redv[w][col][0] = p1; redv[w][col][1] = p2; redv[w][col][2] = p3; }
        __syncthreads();
        float s1 = 0.f, s2 = 0.f, s3 = 0.f;
#pragma unroll
        for (int u16 = 0; u16 < 16; ++u16) {
            s1 += redv[u16][col][0]; s2 += redv[u16][col][1]; s3 += redv[u16][col][2];
        }
        float eps1 = fmaxf(yn - 2.f * s1 + s2, 0.f);
        eps = atot / (b0v + eps1 + s3 + EPS_Sf);
        float ck = ws[o_c + (size_t)b * 9 + k];
        float dk = ws[o_dd + (size_t)b * 9 + k];
#pragma unroll
        for (int r = 0; r < 4; ++r)
            lam[r] = (ck + 1.f) / (dk + Ur[r] * Ur[r] + Ui[r] * Ui[r] + sg[r] + EPS_Sf);
    }
    // ---- |U|, global max ----
    float4 v;
    v.x = sqrtf(Ur[0] * Ur[0] + Ui[0] * Ui[0]);
    v.y = sqrtf(Ur[1] * Ur[1] + Ui[1] * Ui[1]);
    v.z = sqrtf(Ur[2] * Ur[2] + Ui[2] * Ui[2]);
    v.w = sqrtf(Ur[3] * Ur[3] + Ui[3] * Ui[3]);
    *(float4*)&ws[o_Ua + (size_t)b * M_N + w * 16 + quad * 4] = v;
    float lm = fmaxf(fmaxf(v.x, v.y), fmaxf(v.z, v.w));
#pragma unroll
    for (int off = 32; off >= 1; off >>= 1) lm = fmaxf(lm, __shfl_xor(lm, off));
    if (lane == 0) redm[w] = lm;
    __syncthreads();
    if (tid == 0) {
        float mx = redm[0];
#pragma unroll
        for (int i = 1; i < 16; ++i) mx = fmaxf(mx, redm[i]);
        atomicMax((unsigned int*)(ws + o_gm), __float_as_uint(mx));
    }
}

// ---------------- K6: normalize ----------------
__global__ void k_norm(const float* __restrict__ ws, float* __restrict__ out) {
    size_t i = (size_t)blockIdx.x * 256 + threadIdx.x;
    float gm = __uint_as_float(*(const unsigned int*)(ws + o_gm));
    out[i] = ws[o_Ua + i] / (gm + 1e-8f);
}

extern "C" void kernel_launch(void* const* d_in, const int* in_sizes, int n_in,
                              void* d_out, int out_size, void* d_ws, size_t ws_size,
                              hipStream_t stream) {
    (void)in_sizes; (void)n_in; (void)out_size; (void)ws_size;
    const float* Yr  = (const float*)d_in[0];
    const float* Yi  = (const float*)d_in[1];
    const float* Ar  = (const float*)d_in[2];
    const float* Ai  = (const float*)d_in[3];
    const float* w1  = (const float*)d_in[4];
    const float* b1  = (const float*)d_in[5];
    const float* w2  = (const float*)d_in[6];
    const float* b2  = (const float*)d_in[7];
    const float* hcw = (const float*)d_in[8];
    const float* hcb = (const float*)d_in[9];
    const float* hdw = (const float*)d_in[10];
    const float* hdb = (const float*)d_in[11];
    const float* hTw = (const float*)d_in[12];
    const float* hTb = (const float*)d_in[13];
    const float* a0  = (const float*)d_in[14];
    const float* b0  = (const float*)d_in[15];
    float* ws = (float*)d_ws;
    float* out = (float*)d_out;

    hipMemsetAsync((char*)d_ws + o_gm * sizeof(float), 0, 4, stream);
    k_aa    <<<256, 256, 0, stream>>>(Ar, Ai, ws);
    k_w2t   <<<72, 256, 0, stream>>>(w2, ws);
    k_ay    <<<256, 256, 0, stream>>>(Yr, Yi, Ar, Ai, ws);
    k_conv1 <<<2048, 256, 0, stream>>>(w1, b1, ws);
    k_conv2m<<<1024, 128, 0, stream>>>(b2, ws);
    k_fred  <<<512, 256, 0, stream>>>(ws);
    k_cdt   <<<32, 256, 0, stream>>>(hcw, hcb, hdw, hdb, hTw, hTb, ws, out);
    k_iter  <<<128, 1024, 0, stream>>>(a0, b0, ws);
    k_norm  <<<2048, 256, 0, stream>>>(ws, out);
}

// Round 6
// 244.250 us; speedup vs baseline: 6.9542x; 1.3727x over previous
//
#include <hip/hip_runtime.h>
#include <math.h>

#define B_N   2048
#define NM    128
#define M_N   256
#define LNUM  10
#define EPS_Sf 1e-6f

typedef _Float16 half8 __attribute__((ext_vector_type(8)));
typedef float floatx4 __attribute__((ext_vector_type(4)));

// ---------------- workspace layout (float offsets) ----------------
// o_AA: 2 f16 planes of AA in MFMA-A-fragment order [plane][tile16][ks8][lane64][e8]
//       planes: AAr | AAi (65536 halfs each); single f16 (error ~5e-4 rel, budget 0.02)
static constexpr size_t o_AA  = 0;                       // 131072 floats (half used)
static constexpr size_t o_D   = o_AA  + 131072;          // 256
static constexpr size_t o_yn  = o_D   + 256;             // 2048
static constexpr size_t o_AY  = o_yn  + 2048;            // float2[B*M] -> 1048576 floats
static constexpr size_t o_AYt = o_AY  + 1048576;         // [2][256][2048] = 1048576
static constexpr size_t o_w2t = o_AYt + 1048576;         // Wa f16 [oc=64][kk=9][ic=32]
static constexpr size_t o_z1  = o_w2t + 18432;           // z1t f16 [258][2050][32]
static constexpr size_t o_fp  = o_z1  + 16777216;        // [16][64][2048] fp32 partials
static constexpr size_t o_f   = o_fp  + 2097152;         // [64][2048]
static constexpr size_t o_c   = o_f   + 131072;          // [2048][9]
static constexpr size_t o_dd  = o_c   + 18432;           // [2048][9]
static constexpr size_t o_T   = o_dd  + 18432;           // [2048][10]
static constexpr size_t o_Ua  = o_T   + 20480;           // 524288
static constexpr size_t o_gm  = o_Ua  + 524288;          // 1 (uint bits of max)

#define Z1T_RS (2050 * 32)   // z1t row stride in halfs

__device__ __forceinline__ void split2(float x, _Float16& h, _Float16& l) {
    h = (_Float16)x;
    l = (_Float16)(x - (float)h);
}

// ---------------- K0: AA = A^H A -> single-f16 planes in A-fragment order; D = diag ----
__global__ void k_aa(const float* __restrict__ Ar, const float* __restrict__ Ai,
                     float* __restrict__ ws) {
    __shared__ float cr[NM], ci[NM];
    int i = blockIdx.x, j = threadIdx.x;      // i = m row, j = K col
    if (j < NM) { cr[j] = Ar[j * M_N + i]; ci[j] = Ai[j * M_N + i]; }
    __syncthreads();
    float sr = 0.f, si = 0.f;
    for (int n = 0; n < NM; ++n) {
        float ar = Ar[n * M_N + j], ai = Ai[n * M_N + j];
        sr += cr[n] * ar + ci[n] * ai;
        si += cr[n] * ai - ci[n] * ar;
    }
    _Float16* A16 = (_Float16*)(ws + o_AA);
    // fragment order: ((tile*8 + ks)*64 + lane)*8 + e ; lane = quad*16 + (i&15)
    size_t off = ((size_t)((i >> 4) * 8 + (j >> 5)) * 64
                  + (size_t)(((j >> 3) & 3) * 16 + (i & 15))) * 8 + (j & 7);
    A16[off]         = (_Float16)sr;
    A16[65536 + off] = (_Float16)si;
    if (j == i) ws[o_D + i] = sr;
}

// ---------------- K0b: Wa[oc][kk][ic] f16 from w2[oc][ic][3][3] ----------------
__global__ void k_w2t(const float* __restrict__ w2, float* __restrict__ ws) {
    int i = blockIdx.x * 256 + threadIdx.x;
    if (i < 64 * 32 * 9) {
        int oc = i / 288, r = i % 288;
        int ic = r / 9, kk = r % 9;
        _Float16* Wa = (_Float16*)(ws + o_w2t);
        Wa[((size_t)oc * 9 + kk) * 32 + ic] = (_Float16)w2[i];
    }
}

// ---------------- K1: AY = A^H Y, ||Y||^2, transposed layout for conv ----------------
__global__ void k_ay(const float* __restrict__ Yr, const float* __restrict__ Yi,
                     const float* __restrict__ Ar, const float* __restrict__ Ai,
                     float* __restrict__ ws) {
    __shared__ float2 Ys[8][NM];
    int bb0 = blockIdx.x * 8;
    int tid = threadIdx.x;
    for (int i = tid; i < 8 * NM; i += 256) {
        int g = i >> 7, n = i & 127;
        Ys[g][n] = make_float2(Yr[(size_t)(bb0 + g) * NM + n], Yi[(size_t)(bb0 + g) * NM + n]);
    }
    __syncthreads();
    if (tid < 8) {
        float s = 0.f;
        for (int n = 0; n < NM; ++n) { float2 y = Ys[tid][n]; s += y.x * y.x + y.y * y.y; }
        ws[o_yn + bb0 + tid] = s;
    }
    int m = tid;
    float accr[8], acci[8];
#pragma unroll
    for (int g = 0; g < 8; ++g) { accr[g] = 0.f; acci[g] = 0.f; }
    for (int n = 0; n < NM; ++n) {
        float ar = Ar[n * M_N + m], ai = Ai[n * M_N + m];
#pragma unroll
        for (int g = 0; g < 8; ++g) {
            float2 y = Ys[g][n];
            accr[g] += ar * y.x + ai * y.y;
            acci[g] += ar * y.y - ai * y.x;
        }
    }
    float2* AY = (float2*)(ws + o_AY);
#pragma unroll
    for (int g = 0; g < 8; ++g) {
        AY[(size_t)(bb0 + g) * M_N + m] = make_float2(accr[g], acci[g]);
        ws[o_AYt + (size_t)m * B_N + (bb0 + g)] = accr[g];
        ws[o_AYt + 524288 + (size_t)m * B_N + (bb0 + g)] = acci[g];
    }
}

// ---------------- K2: conv1 (2->32) + ReLU -> z1t f16 [m+1][b+1][ic], zero halo ----------
__global__ void k_conv1(const float* __restrict__ w1, const float* __restrict__ b1,
                        float* __restrict__ ws) {
    __shared__ float w1s[576], b1s[32];
    int tid = threadIdx.x;
    for (int i = tid; i < 576; i += 256) w1s[i] = w1[i];
    if (tid < 32) b1s[tid] = b1[tid];
    __syncthreads();
    int gidx = blockIdx.x * 256 + tid;
    int b = gidx & (B_N - 1), m = gidx >> 11;
    const float* xr = ws + o_AYt;
    float x[2][3][3];
#pragma unroll
    for (int c = 0; c < 2; ++c)
#pragma unroll
        for (int dm = 0; dm < 3; ++dm) {
            int mm = m + dm - 1;
#pragma unroll
            for (int db = 0; db < 3; ++db) {
                int bb = b + db - 1;
                x[c][dm][db] = (mm >= 0 && mm < M_N && bb >= 0 && bb < B_N)
                                 ? xr[(size_t)c * 524288 + (size_t)mm * B_N + bb] : 0.f;
            }
        }
    _Float16* z1t = (_Float16*)(ws + o_z1);
    _Float16 zv[32];
    for (int oc = 0; oc < 32; ++oc) {
        float acc = b1s[oc];
#pragma unroll
        for (int c = 0; c < 2; ++c)
#pragma unroll
            for (int dm = 0; dm < 3; ++dm)
#pragma unroll
                for (int db = 0; db < 3; ++db)
                    acc += x[c][dm][db] * w1s[oc * 18 + c * 9 + dm * 3 + db];
        zv[oc] = (_Float16)fmaxf(acc, 0.f);
    }
    _Float16* dst = z1t + (size_t)(m + 1) * Z1T_RS + (size_t)(b + 1) * 32;
#pragma unroll
    for (int v = 0; v < 4; ++v) *(half8*)(dst + v * 8) = *(half8*)(zv + v * 8);
    half8 z8 = (half8)((_Float16)0.f);
    if (m == 0) {
        _Float16* d2 = z1t + (size_t)(b + 1) * 32;
#pragma unroll
        for (int v = 0; v < 4; ++v) *(half8*)(d2 + v * 8) = z8;
        if (b == 0) { _Float16* d3 = z1t;
#pragma unroll
            for (int v = 0; v < 4; ++v) *(half8*)(d3 + v * 8) = z8; }
        if (b == B_N - 1) { _Float16* d3 = z1t + (size_t)2049 * 32;
#pragma unroll
            for (int v = 0; v < 4; ++v) *(half8*)(d3 + v * 8) = z8; }
    }
    if (m == M_N - 1) {
        _Float16* d2 = z1t + (size_t)257 * Z1T_RS + (size_t)(b + 1) * 32;
#pragma unroll
        for (int v = 0; v < 4; ++v) *(half8*)(d2 + v * 8) = z8;
        if (b == 0) { _Float16* d3 = z1t + (size_t)257 * Z1T_RS;
#pragma unroll
            for (int v = 0; v < 4; ++v) *(half8*)(d3 + v * 8) = z8; }
        if (b == B_N - 1) { _Float16* d3 = z1t + (size_t)257 * Z1T_RS + (size_t)2049 * 32;
#pragma unroll
            for (int v = 0; v < 4; ++v) *(half8*)(d3 + v * 8) = z8; }
    }
    if (b == 0) {
        _Float16* d2 = z1t + (size_t)(m + 1) * Z1T_RS;
#pragma unroll
        for (int v = 0; v < 4; ++v) *(half8*)(d2 + v * 8) = z8;
    }
    if (b == B_N - 1) {
        _Float16* d2 = z1t + (size_t)(m + 1) * Z1T_RS + (size_t)2049 * 32;
#pragma unroll
        for (int v = 0; v < 4; ++v) *(half8*)(d2 + v * 8) = z8;
    }
}

// ---------------- K3: conv2 implicit-GEMM MFMA; 16-row m-groups (grid 2048) ----------
#define MFMA16(A,Bv,C) C = __builtin_amdgcn_mfma_f32_16x16x32_f16(A, Bv, C, 0, 0, 0)
__global__ void __launch_bounds__(128)
k_conv2m(const float* __restrict__ b2, float* __restrict__ ws) {
    int tid = threadIdx.x;
    int lane = tid & 63, wv = tid >> 6;
    int col = lane & 15, quad = lane >> 4;
    int bt = blockIdx.x & 127, g = blockIdx.x >> 7;   // g = 0..15
    int b0 = bt * 16, m0 = g * 16;
    int oc0w = wv * 32;
    const _Float16* z1t = (const _Float16*)(ws + o_z1);
    const _Float16* Wa  = (const _Float16*)(ws + o_w2t);

    half8 Af[2][9];
#pragma unroll
    for (int t = 0; t < 2; ++t)
#pragma unroll
        for (int kk = 0; kk < 9; ++kk)
            Af[t][kk] = *(const half8*)(Wa + ((size_t)(oc0w + t * 16 + col) * 9 + kk) * 32 + quad * 8);
    float bias[2][4];
#pragma unroll
    for (int t = 0; t < 2; ++t)
#pragma unroll
        for (int r = 0; r < 4; ++r)
            bias[t][r] = b2[oc0w + t * 16 + quad * 4 + r];

    const _Float16* zb = z1t + (size_t)(b0 + col) * 32 + quad * 8;
    half8 Bf[3][3];
#pragma unroll
    for (int ph = 0; ph < 3; ++ph)
#pragma unroll
        for (int db = 0; db < 3; ++db)
            Bf[ph][db] = *(const half8*)(zb + (size_t)(m0 + ph) * Z1T_RS + (size_t)db * 32);

    floatx4 facc[2];
    facc[0] = (floatx4){0.f, 0.f, 0.f, 0.f};
    facc[1] = (floatx4){0.f, 0.f, 0.f, 0.f};

#pragma unroll
    for (int mm = 0; mm < 16; ++mm) {
        floatx4 a0 = (floatx4){0.f, 0.f, 0.f, 0.f};
        floatx4 a1 = (floatx4){0.f, 0.f, 0.f, 0.f};
#pragma unroll
        for (int dm = 0; dm < 3; ++dm) {
            int ph = (mm + dm) % 3;
#pragma unroll
            for (int db = 0; db < 3; ++db) {
                MFMA16(Af[0][dm * 3 + db], Bf[ph][db], a0);
                MFMA16(Af[1][dm * 3 + db], Bf[ph][db], a1);
            }
        }
#pragma unroll
        for (int r = 0; r < 4; ++r) {
            facc[0][r] += fmaxf(a0[r] + bias[0][r], 0.f);
            facc[1][r] += fmaxf(a1[r] + bias[1][r], 0.f);
        }
        if (mm < 15) {
            int ph = mm % 3;
#pragma unroll
            for (int db = 0; db < 3; ++db)
                Bf[ph][db] = *(const half8*)(zb + (size_t)(m0 + mm + 3) * Z1T_RS + (size_t)db * 32);
        }
    }
    float* fp = ws + o_fp + (size_t)g * 131072;
#pragma unroll
    for (int t = 0; t < 2; ++t)
#pragma unroll
        for (int r = 0; r < 4; ++r)
            fp[(size_t)(oc0w + t * 16 + quad * 4 + r) * B_N + b0 + col] = facc[t][r];
}

// ---------------- K3b: reduce 16 partials -> f = mean over M ----------------
__global__ void k_fred(float* __restrict__ ws) {
    size_t i = (size_t)blockIdx.x * 256 + threadIdx.x;
    float s = 0.f;
    for (int p = 0; p < 16; ++p) s += ws[o_fp + (size_t)p * 131072 + i];
    ws[o_f + i] = s * (1.f / 256.f);
}

// ---------------- K4: c,d,T 1-D convs; one l per block-row (grid 224) ----------------
__global__ void k_cdt(const float* __restrict__ hcw, const float* __restrict__ hcb,
                      const float* __restrict__ hdw, const float* __restrict__ hdb,
                      const float* __restrict__ hTw, const float* __restrict__ hTb,
                      float* __restrict__ ws, float* __restrict__ out) {
    int l = blockIdx.x >> 3;                              // 0..27
    int b = (blockIdx.x & 7) * 256 + threadIdx.x;
    const float* f = ws + o_f;
    const float* w; float bi; int li, kind;
    if (l < 9)       { kind = 0; li = l;      w = hcw + (size_t)li * 192; bi = hcb[li]; }
    else if (l < 18) { kind = 1; li = l - 9;  w = hdw + (size_t)li * 192; bi = hdb[li]; }
    else             { kind = 2; li = l - 18; w = hTw + (size_t)li * 192; bi = hTb[li]; }
    __shared__ float wsm[192];
    for (int i = threadIdx.x; i < 192; i += 256) wsm[i] = w[i];
    __syncthreads();
    float acc = bi;
    bool okL = (b > 0), okR = (b < B_N - 1);
    for (int ic = 0; ic < 64; ++ic) {
        const float* fr = f + (size_t)ic * B_N + b;
        float fm1 = okL ? fr[-1] : 0.f;
        float f0  = fr[0];
        float fp1 = okR ? fr[1] : 0.f;
        acc += fm1 * wsm[ic * 3] + f0 * wsm[ic * 3 + 1] + fp1 * wsm[ic * 3 + 2];
    }
    float v = fmaxf(fabsf(acc), 1e-6f);
    if (kind != 1) v = fminf(v, 100.f);
    if (kind == 0)      { ws[o_c  + (size_t)b * 9  + li] = v; if (b == B_N - 1) out[524288 + li] = v; }
    else if (kind == 1) { ws[o_dd + (size_t)b * 9  + li] = v; if (b == B_N - 1) out[524297 + li] = v; }
    else                { ws[o_T  + (size_t)b * 10 + li] = v; if (b == B_N - 1) out[524306 + li] = v; }
}

// ---------------- K5: 10-layer iteration; AA register-resident, single-f16 ----------------
// Block: 16 batches (cols) x full m=256; wave w owns rows [w*16, w*16+16).
// A slice (2 planes x 8 ks x b128) = 64 VGPRs, loaded ONCE -> zero global traffic in loop.
// U hi/lo staged to LDS in B-fragment order; 8 MFMA per ks.
__global__ void __launch_bounds__(1024, 4)
k_iter(const float* __restrict__ a0p, const float* __restrict__ b0p, float* __restrict__ ws) {
    __shared__ __align__(16) _Float16 Ubf[4][8][64][8];   // 32 KB
    __shared__ float redv[16][16][3];
    __shared__ float redm[16];
    int tid = threadIdx.x;
    int lane = tid & 63, w = tid >> 6;          // w = 0..15 (row tile)
    int col = lane & 15, quad = lane >> 4;
    int b = blockIdx.x * 16 + col;
    const float2* AY = (const float2*)(ws + o_AY);
    const _Float16* Af = (const _Float16*)(ws + o_AA);
    float a0 = a0p[0], b0v = b0p[0];
    float atot = a0 + (float)NM;
    float yn = ws[o_yn + b];
    float eps = a0 / b0v;
    float lam0 = ws[o_c + (size_t)b * 9] / ws[o_dd + (size_t)b * 9];
    // ---- register-resident A slice ----
    half8 Ar8[8], Ai8[8];
#pragma unroll
    for (int ks = 0; ks < 8; ++ks) {
        const _Float16* ab = Af + ((size_t)(w * 8 + ks) * 64 + lane) * 8;
        Ar8[ks] = *(const half8*)(ab);
        Ai8[ks] = *(const half8*)(ab + 65536);
    }
    float Dv[4], ayr[4], ayi[4], lam[4], Ur[4], Ui[4], sg[4], wr_[4], wi_[4];
#pragma unroll
    for (int r = 0; r < 4; ++r) {
        int m = w * 16 + quad * 4 + r;
        Dv[r] = ws[o_D + m];
        float2 a = AY[(size_t)b * M_N + m];
        ayr[r] = a.x; ayi[r] = a.y;
        lam[r] = lam0;
        Ur[r] = 0.f; Ui[r] = 0.f; wr_[r] = 0.f; wi_[r] = 0.f;
    }
    int ksw = w >> 1;
    int quadD = (w & 1) * 2 + (quad >> 1);
    int laneD = quadD * 16 + col;
    int eb = (quad & 1) * 4;
    for (int k = 0; k < LNUM; ++k) {
        float Tk = ws[o_T + (size_t)b * 10 + k];
#pragma unroll
        for (int r = 0; r < 4; ++r) {
            float iv = eps / (eps * Tk + lam[r] + EPS_Sf);
            Ur[r] = iv * (Tk * Ur[r] - wr_[r] + ayr[r]);
            Ui[r] = iv * (Tk * Ui[r] - wi_[r] + ayi[r]);
        }
        if (k == LNUM - 1) break;
        // ---- stage U hi/lo to LDS in B-fragment order ----
        {
            union { _Float16 h[4]; unsigned long long u; } c0, c1, c2, c3;
#pragma unroll
            for (int r = 0; r < 4; ++r) {
                _Float16 h, l;
                split2(Ur[r], h, l); c0.h[r] = h; c1.h[r] = l;
                split2(Ui[r], h, l); c2.h[r] = h; c3.h[r] = l;
            }
            *(unsigned long long*)&Ubf[0][ksw][laneD][eb] = c0.u;
            *(unsigned long long*)&Ubf[1][ksw][laneD][eb] = c1.u;
            *(unsigned long long*)&Ubf[2][ksw][laneD][eb] = c2.u;
            *(unsigned long long*)&Ubf[3][ksw][laneD][eb] = c3.u;
        }
        __syncthreads();
        // ---- matvec: w = AA * U (A in registers, 8 MFMA/ks) ----
        floatx4 wrp = (floatx4){0.f, 0.f, 0.f, 0.f};
        floatx4 wrn = (floatx4){0.f, 0.f, 0.f, 0.f};
        floatx4 wia = (floatx4){0.f, 0.f, 0.f, 0.f};
#pragma unroll
        for (int ks = 0; ks < 8; ++ks) {
            half8 urh = *(const half8*)&Ubf[0][ks][lane][0];
            half8 url = *(const half8*)&Ubf[1][ks][lane][0];
            half8 uih = *(const half8*)&Ubf[2][ks][lane][0];
            half8 uil = *(const half8*)&Ubf[3][ks][lane][0];
            MFMA16(Ar8[ks], urh, wrp);
            MFMA16(Ar8[ks], url, wrp);
            MFMA16(Ai8[ks], uih, wrn);
            MFMA16(Ai8[ks], uil, wrn);
            MFMA16(Ar8[ks], uih, wia);
            MFMA16(Ar8[ks], uil, wia);
            MFMA16(Ai8[ks], urh, wia);
            MFMA16(Ai8[ks], url, wia);
        }
        // ---- per-batch reductions over m ----
        float p1 = 0.f, p2 = 0.f, p3 = 0.f;
#pragma unroll
        for (int r = 0; r < 4; ++r) {
            wr_[r] = wrp[r] - wrn[r];
            wi_[r] = wia[r];
            sg[r] = 1.f / (eps * Dv[r] + lam[r] + EPS_Sf);
            p1 += ayr[r] * Ur[r] + ayi[r] * Ui[r];
            p2 += Ur[r] * wr_[r] + Ui[r] * wi_[r];
            p3 += Dv[r] * sg[r];
        }
        p1 += __shfl_xor(p1, 16); p1 += __shfl_xor(p1, 32);
        p2 += __shfl_xor(p2, 16); p2 += __shfl_xor(p2, 32);
        p3 += __shfl_xor(p3, 16); p3 += __shfl_xor(p3, 32);
        if (lane < 16) { redv[w][col][0] = p1; redv[w][col][1] = p2; redv[w][col][2] = p3; }
        __syncthreads();
        float s1 = 0.f, s2 = 0.f, s3 = 0.f;
#pragma unroll
        for (int u16 = 0; u16 < 16; ++u16) {
            s1 += redv[u16][col][0]; s2 += redv[u16][col][1]; s3 += redv[u16][col][2];
        }
        float eps1 = fmaxf(yn - 2.f * s1 + s2, 0.f);
        eps = atot / (b0v + eps1 + s3 + EPS_Sf);
        float ck = ws[o_c + (size_t)b * 9 + k];
        float dk = ws[o_dd + (size_t)b * 9 + k];
#pragma unroll
        for (int r = 0; r < 4; ++r)
            lam[r] = (ck + 1.f) / (dk + Ur[r] * Ur[r] + Ui[r] * Ui[r] + sg[r] + EPS_Sf);
    }
    // ---- |U|, global max ----
    float4 v;
    v.x = sqrtf(Ur[0] * Ur[0] + Ui[0] * Ui[0]);
    v.y = sqrtf(Ur[1] * Ur[1] + Ui[1] * Ui[1]);
    v.z = sqrtf(Ur[2] * Ur[2] + Ui[2] * Ui[2]);
    v.w = sqrtf(Ur[3] * Ur[3] + Ui[3] * Ui[3]);
    *(float4*)&ws[o_Ua + (size_t)b * M_N + w * 16 + quad * 4] = v;
    float lm = fmaxf(fmaxf(v.x, v.y), fmaxf(v.z, v.w));
#pragma unroll
    for (int off = 32; off >= 1; off >>= 1) lm = fmaxf(lm, __shfl_xor(lm, off));
    if (lane == 0) redm[w] = lm;
    __syncthreads();
    if (tid == 0) {
        float mx = redm[0];
#pragma unroll
        for (int i = 1; i < 16; ++i) mx = fmaxf(mx, redm[i]);
        atomicMax((unsigned int*)(ws + o_gm), __float_as_uint(mx));
    }
}

// ---------------- K6: normalize ----------------
__global__ void k_norm(const float* __restrict__ ws, float* __restrict__ out) {
    size_t i = (size_t)blockIdx.x * 256 + threadIdx.x;
    float gm = __uint_as_float(*(const unsigned int*)(ws + o_gm));
    out[i] = ws[o_Ua + i] / (gm + 1e-8f);
}

extern "C" void kernel_launch(void* const* d_in, const int* in_sizes, int n_in,
                              void* d_out, int out_size, void* d_ws, size_t ws_size,
                              hipStream_t stream) {
    (void)in_sizes; (void)n_in; (void)out_size; (void)ws_size;
    const float* Yr  = (const float*)d_in[0];
    const float* Yi  = (const float*)d_in[1];
    const float* Ar  = (const float*)d_in[2];
    const float* Ai  = (const float*)d_in[3];
    const float* w1  = (const float*)d_in[4];
    const float* b1  = (const float*)d_in[5];
    const float* w2  = (const float*)d_in[6];
    const float* b2  = (const float*)d_in[7];
    const float* hcw = (const float*)d_in[8];
    const float* hcb = (const float*)d_in[9];
    const float* hdw = (const float*)d_in[10];
    const float* hdb = (const float*)d_in[11];
    const float* hTw = (const float*)d_in[12];
    const float* hTb = (const float*)d_in[13];
    const float* a0  = (const float*)d_in[14];
    const float* b0  = (const float*)d_in[15];
    float* ws = (float*)d_ws;
    float* out = (float*)d_out;

    hipMemsetAsync((char*)d_ws + o_gm * sizeof(float), 0, 4, stream);
    k_aa    <<<256, 256, 0, stream>>>(Ar, Ai, ws);
    k_w2t   <<<72, 256, 0, stream>>>(w2, ws);
    k_ay    <<<256, 256, 0, stream>>>(Yr, Yi, Ar, Ai, ws);
    k_conv1 <<<2048, 256, 0, stream>>>(w1, b1, ws);
    k_conv2m<<<2048, 128, 0, stream>>>(b2, ws);
    k_fred  <<<512, 256, 0, stream>>>(ws);
    k_cdt   <<<224, 256, 0, stream>>>(hcw, hcb, hdw, hdb, hTw, hTb, ws, out);
    k_iter  <<<128, 1024, 0, stream>>>(a0, b0, ws);
    k_norm  <<<2048, 256, 0, stream>>>(ws, out);
}

// Round 7
// 242.412 us; speedup vs baseline: 7.0069x; 1.0076x over previous
//
#include <hip/hip_runtime.h>
#include <math.h>

#define B_N   2048
#define NM    128
#define M_N   256
#define LNUM  10
#define EPS_Sf 1e-6f

typedef _Float16 half8 __attribute__((ext_vector_type(8)));
typedef float floatx4 __attribute__((ext_vector_type(4)));

// ---------------- workspace layout (float offsets) ----------------
// o_AA: 2 f16 planes of AA in MFMA-A-fragment order [plane][tile16][ks8][lane64][e8]
static constexpr size_t o_AA  = 0;                       // 131072 floats (half used)
static constexpr size_t o_D   = o_AA  + 131072;          // 256
static constexpr size_t o_yn  = o_D   + 256;             // 2048
static constexpr size_t o_AY  = o_yn  + 2048;            // float2[B*M] -> 1048576 floats
static constexpr size_t o_AYt = o_AY  + 1048576;         // [2][256][2048] = 1048576
static constexpr size_t o_w2t = o_AYt + 1048576;         // Wa f16 [oc=64][kk=9][ic=32]
static constexpr size_t o_z1  = o_w2t + 18432;           // z1t f16 [258][2050][32]
static constexpr size_t o_fp  = o_z1  + 16777216;        // [16][64][2048] fp32 partials
static constexpr size_t o_f   = o_fp  + 2097152;         // [64][2048]
static constexpr size_t o_c   = o_f   + 131072;          // [2048][9]
static constexpr size_t o_dd  = o_c   + 18432;           // [2048][9]
static constexpr size_t o_T   = o_dd  + 18432;           // [2048][10]
static constexpr size_t o_Ua  = o_T   + 20480;           // 524288
static constexpr size_t o_gm  = o_Ua  + 524288;          // 1 (uint bits of max)

#define Z1T_RS (2050 * 32)   // z1t row stride in halfs

// ---------------- K_pre: fused {gm=0, AA->f16 frag, w2 transpose, AY} ----------------
// blocks [0,256) : k_aa rows ; [256,328) : w2t ; [328,584) : k_ay groups
__global__ void k_pre(const float* __restrict__ Ar, const float* __restrict__ Ai,
                      const float* __restrict__ Yr, const float* __restrict__ Yi,
                      const float* __restrict__ w2, float* __restrict__ ws) {
    __shared__ float sb[2048];
    int blk = blockIdx.x;
    int tid = threadIdx.x;
    if (blk < 256) {
        // ---- AA row i = blk ----
        float* cr = sb; float* ci = sb + NM;
        int i = blk, j = tid;
        if (j < NM) { cr[j] = Ar[j * M_N + i]; ci[j] = Ai[j * M_N + i]; }
        __syncthreads();
        float sr = 0.f, si = 0.f;
        for (int n = 0; n < NM; ++n) {
            float ar = Ar[n * M_N + j], ai = Ai[n * M_N + j];
            sr += cr[n] * ar + ci[n] * ai;
            si += cr[n] * ai - ci[n] * ar;
        }
        _Float16* A16 = (_Float16*)(ws + o_AA);
        size_t off = ((size_t)((i >> 4) * 8 + (j >> 5)) * 64
                      + (size_t)(((j >> 3) & 3) * 16 + (i & 15))) * 8 + (j & 7);
        A16[off]         = (_Float16)sr;
        A16[65536 + off] = (_Float16)si;
        if (j == i) ws[o_D + i] = sr;
        if (i == 0 && j == 0) *(unsigned int*)(ws + o_gm) = 0u;  // zero global max
    } else if (blk < 328) {
        int i = (blk - 256) * 256 + tid;
        if (i < 64 * 32 * 9) {
            int oc = i / 288, r = i % 288;
            int ic = r / 9, kk = r % 9;
            _Float16* Wa = (_Float16*)(ws + o_w2t);
            Wa[((size_t)oc * 9 + kk) * 32 + ic] = (_Float16)w2[i];
        }
    } else {
        // ---- AY group ----
        float2* Ys = (float2*)sb;                // [8][NM]
        int bb0 = (blk - 328) * 8;
        for (int i = tid; i < 8 * NM; i += 256) {
            int g = i >> 7, n = i & 127;
            Ys[g * NM + n] = make_float2(Yr[(size_t)(bb0 + g) * NM + n],
                                         Yi[(size_t)(bb0 + g) * NM + n]);
        }
        __syncthreads();
        if (tid < 8) {
            float s = 0.f;
            for (int n = 0; n < NM; ++n) { float2 y = Ys[tid * NM + n]; s += y.x * y.x + y.y * y.y; }
            ws[o_yn + bb0 + tid] = s;
        }
        int m = tid;
        float accr[8], acci[8];
#pragma unroll
        for (int g = 0; g < 8; ++g) { accr[g] = 0.f; acci[g] = 0.f; }
        for (int n = 0; n < NM; ++n) {
            float ar = Ar[n * M_N + m], ai = Ai[n * M_N + m];
#pragma unroll
            for (int g = 0; g < 8; ++g) {
                float2 y = Ys[g * NM + n];
                accr[g] += ar * y.x + ai * y.y;
                acci[g] += ar * y.y - ai * y.x;
            }
        }
        float2* AY = (float2*)(ws + o_AY);
#pragma unroll
        for (int g = 0; g < 8; ++g) {
            AY[(size_t)(bb0 + g) * M_N + m] = make_float2(accr[g], acci[g]);
            ws[o_AYt + (size_t)m * B_N + (bb0 + g)] = accr[g];
            ws[o_AYt + 524288 + (size_t)m * B_N + (bb0 + g)] = acci[g];
        }
    }
}

// ---------------- K2: conv1 (2->32) + ReLU -> z1t f16 [m+1][b+1][ic], zero halo ----------
__global__ void k_conv1(const float* __restrict__ w1, const float* __restrict__ b1,
                        float* __restrict__ ws) {
    __shared__ float w1s[576], b1s[32];
    int tid = threadIdx.x;
    for (int i = tid; i < 576; i += 256) w1s[i] = w1[i];
    if (tid < 32) b1s[tid] = b1[tid];
    __syncthreads();
    int gidx = blockIdx.x * 256 + tid;
    int b = gidx & (B_N - 1), m = gidx >> 11;
    const float* xr = ws + o_AYt;
    float x[2][3][3];
#pragma unroll
    for (int c = 0; c < 2; ++c)
#pragma unroll
        for (int dm = 0; dm < 3; ++dm) {
            int mm = m + dm - 1;
#pragma unroll
            for (int db = 0; db < 3; ++db) {
                int bb = b + db - 1;
                x[c][dm][db] = (mm >= 0 && mm < M_N && bb >= 0 && bb < B_N)
                                 ? xr[(size_t)c * 524288 + (size_t)mm * B_N + bb] : 0.f;
            }
        }
    _Float16* z1t = (_Float16*)(ws + o_z1);
    _Float16 zv[32];
    for (int oc = 0; oc < 32; ++oc) {
        float acc = b1s[oc];
#pragma unroll
        for (int c = 0; c < 2; ++c)
#pragma unroll
            for (int dm = 0; dm < 3; ++dm)
#pragma unroll
                for (int db = 0; db < 3; ++db)
                    acc += x[c][dm][db] * w1s[oc * 18 + c * 9 + dm * 3 + db];
        zv[oc] = (_Float16)fmaxf(acc, 0.f);
    }
    _Float16* dst = z1t + (size_t)(m + 1) * Z1T_RS + (size_t)(b + 1) * 32;
#pragma unroll
    for (int v = 0; v < 4; ++v) *(half8*)(dst + v * 8) = *(half8*)(zv + v * 8);
    half8 z8 = (half8)((_Float16)0.f);
    if (m == 0) {
        _Float16* d2 = z1t + (size_t)(b + 1) * 32;
#pragma unroll
        for (int v = 0; v < 4; ++v) *(half8*)(d2 + v * 8) = z8;
        if (b == 0) { _Float16* d3 = z1t;
#pragma unroll
            for (int v = 0; v < 4; ++v) *(half8*)(d3 + v * 8) = z8; }
        if (b == B_N - 1) { _Float16* d3 = z1t + (size_t)2049 * 32;
#pragma unroll
            for (int v = 0; v < 4; ++v) *(half8*)(d3 + v * 8) = z8; }
    }
    if (m == M_N - 1) {
        _Float16* d2 = z1t + (size_t)257 * Z1T_RS + (size_t)(b + 1) * 32;
#pragma unroll
        for (int v = 0; v < 4; ++v) *(half8*)(d2 + v * 8) = z8;
        if (b == 0) { _Float16* d3 = z1t + (size_t)257 * Z1T_RS;
#pragma unroll
            for (int v = 0; v < 4; ++v) *(half8*)(d3 + v * 8) = z8; }
        if (b == B_N - 1) { _Float16* d3 = z1t + (size_t)257 * Z1T_RS + (size_t)2049 * 32;
#pragma unroll
            for (int v = 0; v < 4; ++v) *(half8*)(d3 + v * 8) = z8; }
    }
    if (b == 0) {
        _Float16* d2 = z1t + (size_t)(m + 1) * Z1T_RS;
#pragma unroll
        for (int v = 0; v < 4; ++v) *(half8*)(d2 + v * 8) = z8;
    }
    if (b == B_N - 1) {
        _Float16* d2 = z1t + (size_t)(m + 1) * Z1T_RS + (size_t)2049 * 32;
#pragma unroll
        for (int v = 0; v < 4; ++v) *(half8*)(d2 + v * 8) = z8;
    }
}

// ---------------- K3: conv2 implicit-GEMM MFMA; 16-row m-groups (grid 2048) ----------
#define MFMA16(A,Bv,C) C = __builtin_amdgcn_mfma_f32_16x16x32_f16(A, Bv, C, 0, 0, 0)
__global__ void __launch_bounds__(128)
k_conv2m(const float* __restrict__ b2, float* __restrict__ ws) {
    int tid = threadIdx.x;
    int lane = tid & 63, wv = tid >> 6;
    int col = lane & 15, quad = lane >> 4;
    int bt = blockIdx.x & 127, g = blockIdx.x >> 7;   // g = 0..15
    int b0 = bt * 16, m0 = g * 16;
    int oc0w = wv * 32;
    const _Float16* z1t = (const _Float16*)(ws + o_z1);
    const _Float16* Wa  = (const _Float16*)(ws + o_w2t);

    half8 Af[2][9];
#pragma unroll
    for (int t = 0; t < 2; ++t)
#pragma unroll
        for (int kk = 0; kk < 9; ++kk)
            Af[t][kk] = *(const half8*)(Wa + ((size_t)(oc0w + t * 16 + col) * 9 + kk) * 32 + quad * 8);
    float bias[2][4];
#pragma unroll
    for (int t = 0; t < 2; ++t)
#pragma unroll
        for (int r = 0; r < 4; ++r)
            bias[t][r] = b2[oc0w + t * 16 + quad * 4 + r];

    const _Float16* zb = z1t + (size_t)(b0 + col) * 32 + quad * 8;
    half8 Bf[3][3];
#pragma unroll
    for (int ph = 0; ph < 3; ++ph)
#pragma unroll
        for (int db = 0; db < 3; ++db)
            Bf[ph][db] = *(const half8*)(zb + (size_t)(m0 + ph) * Z1T_RS + (size_t)db * 32);

    floatx4 facc[2];
    facc[0] = (floatx4){0.f, 0.f, 0.f, 0.f};
    facc[1] = (floatx4){0.f, 0.f, 0.f, 0.f};

#pragma unroll
    for (int mm = 0; mm < 16; ++mm) {
        floatx4 a0 = (floatx4){0.f, 0.f, 0.f, 0.f};
        floatx4 a1 = (floatx4){0.f, 0.f, 0.f, 0.f};
#pragma unroll
        for (int dm = 0; dm < 3; ++dm) {
            int ph = (mm + dm) % 3;
#pragma unroll
            for (int db = 0; db < 3; ++db) {
                MFMA16(Af[0][dm * 3 + db], Bf[ph][db], a0);
                MFMA16(Af[1][dm * 3 + db], Bf[ph][db], a1);
            }
        }
#pragma unroll
        for (int r = 0; r < 4; ++r) {
            facc[0][r] += fmaxf(a0[r] + bias[0][r], 0.f);
            facc[1][r] += fmaxf(a1[r] + bias[1][r], 0.f);
        }
        if (mm < 15) {
            int ph = mm % 3;
#pragma unroll
            for (int db = 0; db < 3; ++db)
                Bf[ph][db] = *(const half8*)(zb + (size_t)(m0 + mm + 3) * Z1T_RS + (size_t)db * 32);
        }
    }
    float* fp = ws + o_fp + (size_t)g * 131072;
#pragma unroll
    for (int t = 0; t < 2; ++t)
#pragma unroll
        for (int r = 0; r < 4; ++r)
            fp[(size_t)(oc0w + t * 16 + quad * 4 + r) * B_N + b0 + col] = facc[t][r];
}

// ---------------- K3b: reduce 16 partials -> f = mean over M ----------------
__global__ void k_fred(float* __restrict__ ws) {
    size_t i = (size_t)blockIdx.x * 256 + threadIdx.x;
    float s = 0.f;
    for (int p = 0; p < 16; ++p) s += ws[o_fp + (size_t)p * 131072 + i];
    ws[o_f + i] = s * (1.f / 256.f);
}

// ---------------- K4: c,d,T 1-D convs; one l per block-row (grid 224) ----------------
__global__ void k_cdt(const float* __restrict__ hcw, const float* __restrict__ hcb,
                      const float* __restrict__ hdw, const float* __restrict__ hdb,
                      const float* __restrict__ hTw, const float* __restrict__ hTb,
                      float* __restrict__ ws, float* __restrict__ out) {
    int l = blockIdx.x >> 3;                              // 0..27
    int b = (blockIdx.x & 7) * 256 + threadIdx.x;
    const float* f = ws + o_f;
    const float* w; float bi; int li, kind;
    if (l < 9)       { kind = 0; li = l;      w = hcw + (size_t)li * 192; bi = hcb[li]; }
    else if (l < 18) { kind = 1; li = l - 9;  w = hdw + (size_t)li * 192; bi = hdb[li]; }
    else             { kind = 2; li = l - 18; w = hTw + (size_t)li * 192; bi = hTb[li]; }
    __shared__ float wsm[192];
    for (int i = threadIdx.x; i < 192; i += 256) wsm[i] = w[i];
    __syncthreads();
    float acc = bi;
    bool okL = (b > 0), okR = (b < B_N - 1);
    for (int ic = 0; ic < 64; ++ic) {
        const float* fr = f + (size_t)ic * B_N + b;
        float fm1 = okL ? fr[-1] : 0.f;
        float f0  = fr[0];
        float fp1 = okR ? fr[1] : 0.f;
        acc += fm1 * wsm[ic * 3] + f0 * wsm[ic * 3 + 1] + fp1 * wsm[ic * 3 + 2];
    }
    float v = fmaxf(fabsf(acc), 1e-6f);
    if (kind != 1) v = fminf(v, 100.f);
    if (kind == 0)      { ws[o_c  + (size_t)b * 9  + li] = v; if (b == B_N - 1) out[524288 + li] = v; }
    else if (kind == 1) { ws[o_dd + (size_t)b * 9  + li] = v; if (b == B_N - 1) out[524297 + li] = v; }
    else                { ws[o_T  + (size_t)b * 10 + li] = v; if (b == B_N - 1) out[524306 + li] = v; }
}

// ---------------- K5: 10-layer iteration; AA + U single-f16, vectorized reduction ------
// Block: 16 batches (cols) x full m=256; wave w owns rows [w*16, w*16+16).
// A slice register-resident (64 VGPR). U staged single-f16 (2 comps) in B-frag order.
// 4 MFMA per ks (wrp, wrn, wia split in two). redv [col][52] -> 12x ds_read_b128.
__global__ void __launch_bounds__(1024, 4)
k_iter(const float* __restrict__ a0p, const float* __restrict__ b0p, float* __restrict__ ws) {
    __shared__ __align__(16) _Float16 Ubf[2][8][64][8];   // 16 KB
    __shared__ __align__(16) float redv[16][52];          // 3.3 KB
    __shared__ float redm[16];
    int tid = threadIdx.x;
    int lane = tid & 63, w = tid >> 6;          // w = 0..15 (row tile)
    int col = lane & 15, quad = lane >> 4;
    int b = blockIdx.x * 16 + col;
    const float2* AY = (const float2*)(ws + o_AY);
    const _Float16* Af = (const _Float16*)(ws + o_AA);
    float a0 = a0p[0], b0v = b0p[0];
    float atot = a0 + (float)NM;
    float yn = ws[o_yn + b];
    float eps = a0 / b0v;
    float lam0 = ws[o_c + (size_t)b * 9] / ws[o_dd + (size_t)b * 9];
    // ---- register-resident A slice ----
    half8 Ar8[8], Ai8[8];
#pragma unroll
    for (int ks = 0; ks < 8; ++ks) {
        const _Float16* ab = Af + ((size_t)(w * 8 + ks) * 64 + lane) * 8;
        Ar8[ks] = *(const half8*)(ab);
        Ai8[ks] = *(const half8*)(ab + 65536);
    }
    float Dv[4], ayr[4], ayi[4], lam[4], Ur[4], Ui[4], sg[4], wr_[4], wi_[4];
#pragma unroll
    for (int r = 0; r < 4; ++r) {
        int m = w * 16 + quad * 4 + r;
        Dv[r] = ws[o_D + m];
        float2 a = AY[(size_t)b * M_N + m];
        ayr[r] = a.x; ayi[r] = a.y;
        lam[r] = lam0;
        Ur[r] = 0.f; Ui[r] = 0.f; wr_[r] = 0.f; wi_[r] = 0.f;
    }
    int ksw = w >> 1;
    int quadD = (w & 1) * 2 + (quad >> 1);
    int laneD = quadD * 16 + col;
    int eb = (quad & 1) * 4;
    for (int k = 0; k < LNUM; ++k) {
        float Tk = ws[o_T + (size_t)b * 10 + k];
#pragma unroll
        for (int r = 0; r < 4; ++r) {
            float iv = eps / (eps * Tk + lam[r] + EPS_Sf);
            Ur[r] = iv * (Tk * Ur[r] - wr_[r] + ayr[r]);
            Ui[r] = iv * (Tk * Ui[r] - wi_[r] + ayi[r]);
        }
        if (k == LNUM - 1) break;
        // ---- stage U (single f16) to LDS in B-fragment order ----
        {
            union { _Float16 h[4]; unsigned long long u; } c0, c2;
#pragma unroll
            for (int r = 0; r < 4; ++r) {
                c0.h[r] = (_Float16)Ur[r];
                c2.h[r] = (_Float16)Ui[r];
            }
            *(unsigned long long*)&Ubf[0][ksw][laneD][eb] = c0.u;
            *(unsigned long long*)&Ubf[1][ksw][laneD][eb] = c2.u;
        }
        __syncthreads();
        // ---- matvec: w = AA * U (4 MFMA/ks) ----
        floatx4 wrp = (floatx4){0.f, 0.f, 0.f, 0.f};
        floatx4 wrn = (floatx4){0.f, 0.f, 0.f, 0.f};
        floatx4 wia1 = (floatx4){0.f, 0.f, 0.f, 0.f};
        floatx4 wia2 = (floatx4){0.f, 0.f, 0.f, 0.f};
#pragma unroll
        for (int ks = 0; ks < 8; ++ks) {
            half8 urh = *(const half8*)&Ubf[0][ks][lane][0];
            half8 uih = *(const half8*)&Ubf[1][ks][lane][0];
            MFMA16(Ar8[ks], urh, wrp);
            MFMA16(Ai8[ks], uih, wrn);
            MFMA16(Ar8[ks], uih, wia1);
            MFMA16(Ai8[ks], urh, wia2);
        }
        // ---- per-batch reductions over m ----
        float p1 = 0.f, p2 = 0.f, p3 = 0.f;
#pragma unroll
        for (int r = 0; r < 4; ++r) {
            wr_[r] = wrp[r] - wrn[r];
            wi_[r] = wia1[r] + wia2[r];
            sg[r] = 1.f / (eps * Dv[r] + lam[r] + EPS_Sf);
            p1 += ayr[r] * Ur[r] + ayi[r] * Ui[r];
            p2 += Ur[r] * wr_[r] + Ui[r] * wi_[r];
            p3 += Dv[r] * sg[r];
        }
        p1 += __shfl_xor(p1, 16); p1 += __shfl_xor(p1, 32);
        p2 += __shfl_xor(p2, 16); p2 += __shfl_xor(p2, 32);
        p3 += __shfl_xor(p3, 16); p3 += __shfl_xor(p3, 32);
        if (lane < 16) {
            redv[col][w * 3]     = p1;
            redv[col][w * 3 + 1] = p2;
            redv[col][w * 3 + 2] = p3;
        }
        __syncthreads();
        float s[3] = {0.f, 0.f, 0.f};
#pragma unroll
        for (int j = 0; j < 12; ++j) {
            floatx4 v4 = *(const floatx4*)&redv[col][j * 4];
#pragma unroll
            for (int e = 0; e < 4; ++e) s[(j * 4 + e) % 3] += v4[e];
        }
        float eps1 = fmaxf(yn - 2.f * s[0] + s[1], 0.f);
        eps = atot / (b0v + eps1 + s[2] + EPS_Sf);
        float ck = ws[o_c + (size_t)b * 9 + k];
        float dk = ws[o_dd + (size_t)b * 9 + k];
#pragma unroll
        for (int r = 0; r < 4; ++r)
            lam[r] = (ck + 1.f) / (dk + Ur[r] * Ur[r] + Ui[r] * Ui[r] + sg[r] + EPS_Sf);
    }
    // ---- |U|, global max ----
    float4 v;
    v.x = sqrtf(Ur[0] * Ur[0] + Ui[0] * Ui[0]);
    v.y = sqrtf(Ur[1] * Ur[1] + Ui[1] * Ui[1]);
    v.z = sqrtf(Ur[2] * Ur[2] + Ui[2] * Ui[2]);
    v.w = sqrtf(Ur[3] * Ur[3] + Ui[3] * Ui[3]);
    *(float4*)&ws[o_Ua + (size_t)b * M_N + w * 16 + quad * 4] = v;
    float lm = fmaxf(fmaxf(v.x, v.y), fmaxf(v.z, v.w));
#pragma unroll
    for (int off = 32; off >= 1; off >>= 1) lm = fmaxf(lm, __shfl_xor(lm, off));
    if (lane == 0) redm[w] = lm;
    __syncthreads();
    if (tid == 0) {
        float mx = redm[0];
#pragma unroll
        for (int i = 1; i < 16; ++i) mx = fmaxf(mx, redm[i]);
        atomicMax((unsigned int*)(ws + o_gm), __float_as_uint(mx));
    }
}

// ---------------- K6: normalize ----------------
__global__ void k_norm(const float* __restrict__ ws, float* __restrict__ out) {
    size_t i = (size_t)blockIdx.x * 256 + threadIdx.x;
    float gm = __uint_as_float(*(const unsigned int*)(ws + o_gm));
    out[i] = ws[o_Ua + i] / (gm + 1e-8f);
}

extern "C" void kernel_launch(void* const* d_in, const int* in_sizes, int n_in,
                              void* d_out, int out_size, void* d_ws, size_t ws_size,
                              hipStream_t stream) {
    (void)in_sizes; (void)n_in; (void)out_size; (void)ws_size;
    const float* Yr  = (const float*)d_in[0];
    const float* Yi  = (const float*)d_in[1];
    const float* Ar  = (const float*)d_in[2];
    const float* Ai  = (const float*)d_in[3];
    const float* w1  = (const float*)d_in[4];
    const float* b1  = (const float*)d_in[5];
    const float* w2  = (const float*)d_in[6];
    const float* b2  = (const float*)d_in[7];
    const float* hcw = (const float*)d_in[8];
    const float* hcb = (const float*)d_in[9];
    const float* hdw = (const float*)d_in[10];
    const float* hdb = (const float*)d_in[11];
    const float* hTw = (const float*)d_in[12];
    const float* hTb = (const float*)d_in[13];
    const float* a0  = (const float*)d_in[14];
    const float* b0  = (const float*)d_in[15];
    float* ws = (float*)d_ws;
    float* out = (float*)d_out;

    k_pre   <<<584, 256, 0, stream>>>(Ar, Ai, Yr, Yi, w2, ws);
    k_conv1 <<<2048, 256, 0, stream>>>(w1, b1, ws);
    k_conv2m<<<2048, 128, 0, stream>>>(b2, ws);
    k_fred  <<<512, 256, 0, stream>>>(ws);
    k_cdt   <<<224, 256, 0, stream>>>(hcw, hcb, hdw, hdb, hTw, hTb, ws, out);
    k_iter  <<<128, 1024, 0, stream>>>(a0, b0, ws);
    k_norm  <<<2048, 256, 0, stream>>>(ws, out);
}